// Round 3
// baseline (686.770 us; speedup 1.0000x reference)
//
#include <hip/hip_runtime.h>

#define NVOX 200000
#define TM 128
#define NBLK 1563   // ceil(200000/128)  (fallback tiers)
#define BPS 512     // blocks per stream (fused tier); grid = 1024 = 4 blk/CU x 256
#define NREP 32     // stats-accumulator replicas
#define STG 4224    // floats per stage: 32*128 replicas + 64 scale + 64 shift

typedef unsigned short u16;
typedef unsigned int u32;
typedef __bf16 bf16x8 __attribute__((ext_vector_type(8)));
typedef float f32x16 __attribute__((ext_vector_type(16)));

__device__ __forceinline__ float bf2f(u16 h) { return __uint_as_float(((u32)h) << 16); }
__device__ __forceinline__ u16 f2bf(float x) {
  u32 u = __float_as_uint(x);
  u32 r = u + 0x7fffu + ((u >> 16) & 1u);   // RNE
  return (u16)(r >> 16);
}
__device__ __forceinline__ uint4 cvt8(uint4 a, uint4 b) {
  const float* fa = (const float*)&a;
  const float* fb = (const float*)&b;
  uint4 r;
  u16* q = (u16*)&r;
#pragma unroll
  for (int j = 0; j < 4; ++j) { q[j] = f2bf(fa[j]); q[4 + j] = f2bf(fb[j]); }
  return r;
}

// ---------------------------------------------------------------------------
// Fused conv pair, round 9: register-budgeted wide waves at full occupancy.
//  - taps outer, weights resident in 8 VGPRs per tap (bias frags JIT)
//  - 2 groups (64 rows) per wave in pass A + 1 group pass B (+1 for 106
//    permuted waves, pass C): 6250 groups / 2048 waves per stream
//  - register plan: 4 accs (64) + wreg (32) + X (16) + misc ~ 126 <= 128
//    -> 4 waves/SIMD -> 4 blocks/CU -> grid 1024 = ONE resident generation
//  - no row-bound checks: 200000 = 6250 * 32 exactly
// PHASE 0 (convA): raw weights; both streams -> bf16 + stats.
// PHASE 1 (convB): folded weights (+bias K-step); stream A -> fp32 out,
//                  stream B -> bf16; stats for both.
// ---------------------------------------------------------------------------
template <int PHASE>
__global__ __launch_bounds__(256, 4)
void conv_fused(const u16* __restrict__ inA, const u16* __restrict__ inB,
                const int* __restrict__ nbrA, const int* __restrict__ nbrB,
                const u16* __restrict__ wfA, const u16* __restrict__ wfB,
                const u16* __restrict__ zrow,
                void* yA, void* yB, float* __restrict__ stA, float* __restrict__ stB) {
  __shared__ float sred[4][128];

  const int tid = threadIdx.x;
  const int bid = blockIdx.x;
  const bool hB = (bid >= BPS);
  const int blk = hB ? bid - BPS : bid;
  const u16* f = hB ? inB : inA;
  const int* nbr = hB ? nbrB : nbrA;
  const u16* wf = hB ? wfB : wfA;
  float* st = hB ? stB : stA;

  const int wv = tid >> 6;
  const int lane = tid & 63;
  const int lrow = lane & 31;
  const int lq = lane >> 5;
  const int W = blk * 4 + wv;          // wave id within stream, [0, 2048)

  constexpr bool FOLDED = (PHASE == 1);
  constexpr int KSTRIDE = FOLDED ? 5120 : 4096;
  const bool f32out = (PHASE == 1) && !hB;
  float* yf = (float*)yA;
  u16* yb = (u16*)(hB ? yB : yA);

  float s0 = 0.f, q0 = 0.f, s1 = 0.f, q1 = 0.f;

  auto G = [&](uint4 (&d)[4], int id) {
    const u16* p = (id < NVOX) ? (f + (size_t)id * 64) : zrow;
    p += lq * 8;
    d[0] = *(const uint4*)(p);
    d[1] = *(const uint4*)(p + 16);
    d[2] = *(const uint4*)(p + 32);
    d[3] = *(const uint4*)(p + 48);
  };
  auto MMA = [&](f32x16& c0, f32x16& c1, const uint4 (&s)[4], int id,
                 const bf16x8* wr, const u16* wb) {
#pragma unroll
    for (int ksi = 0; ksi < 4; ++ksi) {
      bf16x8 a = __builtin_bit_cast(bf16x8, s[ksi]);
      c0 = __builtin_amdgcn_mfma_f32_32x32x16_bf16(a, wr[ksi * 2], c0, 0, 0, 0);
      c1 = __builtin_amdgcn_mfma_f32_32x32x16_bf16(a, wr[ksi * 2 + 1], c1, 0, 0, 0);
    }
    if constexpr (FOLDED) {   // bias channel: A = 1[exists] at (lq=0, j=0); B JIT
      uint4 a4 = make_uint4(0u, 0u, 0u, 0u);
      if (lq == 0 && id < NVOX) ((u16*)&a4)[0] = 0x3F80u;
      bf16x8 a = __builtin_bit_cast(bf16x8, a4);
      bf16x8 b0 = __builtin_bit_cast(bf16x8, *(const uint4*)(wb + 8 * 512 + lane * 8));
      bf16x8 b1 = __builtin_bit_cast(bf16x8, *(const uint4*)(wb + 9 * 512 + lane * 8));
      c0 = __builtin_amdgcn_mfma_f32_32x32x16_bf16(a, b0, c0, 0, 0, 0);
      c1 = __builtin_amdgcn_mfma_f32_32x32x16_bf16(a, b1, c1, 0, 0, 0);
    }
  };
  // Epilogue. C/D (32x32): col = lane&31, row = (reg&3) + 8*(reg>>2) + 4*(lane>>5)
  auto EPI = [&](const f32x16& c0, const f32x16& c1, int g) {
    const int row0 = g * 32 + 4 * lq;
#pragma unroll
    for (int r = 0; r < 16; ++r) {
      float v = c0[r]; v = v > 0.f ? v : 0.01f * v;
      float w = c1[r]; w = w > 0.f ? w : 0.01f * w;
      s0 += v; q0 += v * v; s1 += w; q1 += w * w;
      const int row = row0 + (r & 3) + 8 * (r >> 2);
      if (f32out) {
        yf[(size_t)row * 64 + lrow] = v;
        yf[(size_t)row * 64 + 32 + lrow] = w;
      } else {
        yb[(size_t)row * 64 + lrow] = f2bf(v);
        yb[(size_t)row * 64 + 32 + lrow] = f2bf(w);
      }
    }
  };

  const f32x16 zz = {0.f, 0.f, 0.f, 0.f, 0.f, 0.f, 0.f, 0.f,
                     0.f, 0.f, 0.f, 0.f, 0.f, 0.f, 0.f, 0.f};

  // One pass over the 9 taps for 1 or 2 groups (two = compile-time at inline)
  auto PASS = [&](int gA, int gB, bool two) {
    f32x16 c00 = zz, c01 = zz, c10 = zz, c11 = zz;
    const int grA = gA * 32 + lrow;
    const int grB = gB * 32 + lrow;
    int icA = nbr[grA * 9];
    int icB = two ? nbr[grB * 9] : NVOX;
    uint4 X[4];
    for (int k = 0; k < 9; ++k) {
      const u16* wb = wf + k * KSTRIDE;
      bf16x8 wreg[8];
#pragma unroll
      for (int fi = 0; fi < 8; ++fi)
        wreg[fi] = __builtin_bit_cast(bf16x8, *(const uint4*)(wb + fi * 512 + lane * 8));
      int inA = (k < 8) ? nbr[grA * 9 + k + 1] : NVOX;
      int inB = (two && k < 8) ? nbr[grB * 9 + k + 1] : NVOX;
      const bool lA = (k == 4) || (__ballot(icA < NVOX) != 0ull);
      const bool lB = two && ((k == 4) || (__ballot(icB < NVOX) != 0ull));
      if (lA) { G(X, icA); MMA(c00, c01, X, icA, wreg, wb); }
      if (lB) { G(X, icB); MMA(c10, c11, X, icB, wreg, wb); }
      icA = inA; icB = inB;
    }
    EPI(c00, c01, gA);
    if (two) EPI(c10, c11, gB);
  };

  // pass A: groups [0, 4096); pass B: [4096, 6144); pass C: [6144, 6250)
  PASS(2 * W, 2 * W + 1, true);
  PASS(4096 + W, 0, false);
  const int P = (W * 1321) & 2047;   // odd multiplier -> bijection on [0,2048)
  if (P < 106) PASS(6144 + P, 0, false);

  s0 += __shfl_xor(s0, 32); q0 += __shfl_xor(q0, 32);
  s1 += __shfl_xor(s1, 32); q1 += __shfl_xor(q1, 32);
  if (lq == 0) {
    sred[wv][lrow] = s0; sred[wv][32 + lrow] = s1;
    sred[wv][64 + lrow] = q0; sred[wv][96 + lrow] = q1;
  }
  __syncthreads();
  if (tid < 128) {
    int which = tid >> 6, c = tid & 63;
    float v = sred[0][which * 64 + c] + sred[1][which * 64 + c] +
              sred[2][which * 64 + c] + sred[3][which * 64 + c];
    atomicAdd(&st[(bid & (NREP - 1)) * 128 + which * 64 + c], v);
  }
}

// ---- round-6 serial conv (fallback tiers) ---------------------------------
template <bool IN_F32, bool FOLDED, int MODE>
__global__ __launch_bounds__(256, 4)
void conv_k(const void* __restrict__ fv, const int* __restrict__ nbr,
            const u16* __restrict__ wf, void* yv, float* __restrict__ st,
            float* io, const float* __restrict__ affD,
            const float* __restrict__ affB) {
  __shared__ __align__(16) float fb[128 * 68];
  __shared__ float sred[4][128];

  const int tid = threadIdx.x;
  const int wv = tid >> 6;
  const int lane = tid & 63;
  const int lrow = lane & 31;
  const int lq = lane >> 5;
  const int base = blockIdx.x * TM;
  const int gr = base + wv * 32 + lrow;

  int ids[9];
#pragma unroll
  for (int j = 0; j < 9; ++j) ids[j] = (gr < NVOX) ? nbr[gr * 9 + j] : NVOX;

  f32x16 acc0 = {0.f, 0.f, 0.f, 0.f, 0.f, 0.f, 0.f, 0.f,
                 0.f, 0.f, 0.f, 0.f, 0.f, 0.f, 0.f, 0.f};
  f32x16 acc1 = acc0;
  constexpr int KSTRIDE = FOLDED ? 5120 : 4096;

#pragma unroll
  for (int k = 0; k < 9; ++k) {
    if (k != 4) {
      if (__ballot(ids[k] < NVOX) == 0ull) continue;
    }
    const int id = ids[k];
    const bool ok = id < NVOX;
    uint4 af[4];
    if constexpr (IN_F32) {
      const float* p = (const float*)fv + (size_t)id * 64 + lq * 8;
#pragma unroll
      for (int ksi = 0; ksi < 4; ++ksi) {
        uint4 v0 = make_uint4(0u, 0u, 0u, 0u), v1 = v0;
        if (ok) { v0 = *(const uint4*)(p + ksi * 16); v1 = *(const uint4*)(p + ksi * 16 + 4); }
        af[ksi] = cvt8(v0, v1);
      }
    } else {
      const u16* p = (const u16*)fv + (size_t)id * 64 + lq * 8;
#pragma unroll
      for (int ksi = 0; ksi < 4; ++ksi) {
        uint4 v = make_uint4(0u, 0u, 0u, 0u);
        if (ok) v = *(const uint4*)(p + ksi * 16);
        af[ksi] = v;
      }
    }
    const u16* wb = wf + k * KSTRIDE;
#pragma unroll
    for (int ksi = 0; ksi < 4; ++ksi) {
      bf16x8 a = __builtin_bit_cast(bf16x8, af[ksi]);
      bf16x8 b0 = __builtin_bit_cast(bf16x8, *(const uint4*)(wb + (ksi * 2) * 512 + lane * 8));
      bf16x8 b1 = __builtin_bit_cast(bf16x8, *(const uint4*)(wb + (ksi * 2 + 1) * 512 + lane * 8));
      acc0 = __builtin_amdgcn_mfma_f32_32x32x16_bf16(a, b0, acc0, 0, 0, 0);
      acc1 = __builtin_amdgcn_mfma_f32_32x32x16_bf16(a, b1, acc1, 0, 0, 0);
    }
    if constexpr (FOLDED) {
      uint4 a4 = make_uint4(0u, 0u, 0u, 0u);
      if (lq == 0 && ok) ((u16*)&a4)[0] = 0x3F80u;
      bf16x8 a = __builtin_bit_cast(bf16x8, a4);
      bf16x8 b0 = __builtin_bit_cast(bf16x8, *(const uint4*)(wb + 8 * 512 + lane * 8));
      bf16x8 b1 = __builtin_bit_cast(bf16x8, *(const uint4*)(wb + 9 * 512 + lane * 8));
      acc0 = __builtin_amdgcn_mfma_f32_32x32x16_bf16(a, b0, acc0, 0, 0, 0);
      acc1 = __builtin_amdgcn_mfma_f32_32x32x16_bf16(a, b1, acc1, 0, 0, 0);
    }
  }

  const int cc0 = lrow, cc1 = 32 + lrow;
  float aD0 = 0.f, aD1 = 0.f, hD0 = 0.f, hD1 = 0.f;
  if constexpr (MODE == 2) {
    aD0 = affD[cc0]; hD0 = affD[64 + cc0];
    aD1 = affD[cc1]; hD1 = affD[64 + cc1];
  }
  float s0 = 0.f, q0 = 0.f, s1 = 0.f, q1 = 0.f;
  float vout[2][16];
#pragma unroll
  for (int r = 0; r < 16; ++r) {
    float v = acc0[r]; v = v > 0.f ? v : 0.01f * v;
    s0 += v; q0 += v * v; vout[0][r] = v;
    float w = acc1[r]; w = w > 0.f ? w : 0.01f * w;
    s1 += w; q1 += w * w; vout[1][r] = w;
  }
  if constexpr (MODE != 2) {
    s0 += __shfl_xor(s0, 32); q0 += __shfl_xor(q0, 32);
    s1 += __shfl_xor(s1, 32); q1 += __shfl_xor(q1, 32);
    if (lq == 0) {
      sred[wv][lrow] = s0; sred[wv][32 + lrow] = s1;
      sred[wv][64 + lrow] = q0; sred[wv][96 + lrow] = q1;
    }
  }
  if constexpr (MODE == 0) {
    u16* bb = (u16*)fb;
#pragma unroll
    for (int r = 0; r < 16; ++r) {
      int rowD = 32 * wv + (r & 3) + 8 * (r >> 2) + 4 * lq;
      bb[rowD * 72 + cc0] = f2bf(vout[0][r]);
      bb[rowD * 72 + cc1] = f2bf(vout[1][r]);
    }
  } else if constexpr (MODE == 2 || MODE == 3) {
#pragma unroll
    for (int r = 0; r < 16; ++r) {
      int rowD = 32 * wv + (r & 3) + 8 * (r >> 2) + 4 * lq;
      float v0 = vout[0][r], v1 = vout[1][r];
      if constexpr (MODE == 2) { v0 = fmaf(v0, aD0, hD0); v1 = fmaf(v1, aD1, hD1); }
      fb[rowD * 68 + cc0] = v0;
      fb[rowD * 68 + cc1] = v1;
    }
  }
  __syncthreads();

  const int trow = tid >> 3, cp = tid & 7;
  if constexpr (MODE == 0) {
    u16* y = (u16*)yv;
    const u16* bb = (const u16*)fb;
#pragma unroll
    for (int it = 0; it < 4; ++it) {
      int r = it * 32 + trow, row = base + r;
      if (row < NVOX)
        *(uint4*)(y + (size_t)row * 64 + cp * 8) = *(const uint4*)(bb + r * 72 + cp * 8);
    }
  }
  if constexpr (MODE == 3) {
    float* y = (float*)yv;
#pragma unroll
    for (int it = 0; it < 4; ++it) {
      int r = it * 32 + trow, row = base + r;
      if (row < NVOX) {
        *(float4*)(y + (size_t)row * 64 + cp * 8) = *(const float4*)(fb + r * 68 + cp * 8);
        *(float4*)(y + (size_t)row * 64 + cp * 8 + 4) = *(const float4*)(fb + r * 68 + cp * 8 + 4);
      }
    }
  }
  if constexpr (MODE == 2) {
    float* y = (float*)yv;
#pragma unroll
    for (int it = 0; it < 4; ++it) {
      int r = it * 32 + trow, row = base + r;
      if (row < NVOX) {
        float t[8], p[8], o[8];
        *(float4*)&t[0] = *(const float4*)(fb + r * 68 + cp * 8);
        *(float4*)&t[4] = *(const float4*)(fb + r * 68 + cp * 8 + 4);
        *(float4*)&p[0] = *(const float4*)(io + (size_t)row * 64 + cp * 8);
        *(float4*)&p[4] = *(const float4*)(io + (size_t)row * 64 + cp * 8 + 4);
#pragma unroll
        for (int j = 0; j < 8; ++j) {
          int c = cp * 8 + j;
          o[j] = t[j] + fmaf(p[j], affB[c], affB[64 + c]);
        }
        *(float4*)(y + (size_t)row * 64 + cp * 8) = *(const float4*)&o[0];
        *(float4*)(y + (size_t)row * 64 + cp * 8 + 4) = *(const float4*)&o[4];
      }
    }
  }
  if constexpr (MODE != 2) {
    if (tid < 128) {
      int which = tid >> 6, c = tid & 63;
      float v = sred[0][which * 64 + c] + sred[1][which * 64 + c] +
                sred[2][which * 64 + c] + sred[3][which * 64 + c];
      atomicAdd(&st[(blockIdx.x & (NREP - 1)) * 128 + which * 64 + c], v);
    }
  }
}

// prep: feat fp32 -> bf16, raw weight fragments (w1, w2), zero stats + zero row
__global__ void prep_all(const float* __restrict__ feat, const float* __restrict__ w1,
                         const float* __restrict__ w2, u16* __restrict__ wf,
                         u16* __restrict__ F, float* __restrict__ st,
                         u16* __restrict__ zr, int cvt_blocks) {
  const int bid = blockIdx.x, tid = threadIdx.x;
  if (bid < cvt_blocks) {
    int i8 = (bid * 256 + tid) * 8;
    if (i8 < NVOX * 64) {
      uint4 a = *(const uint4*)(feat + i8);
      uint4 b = *(const uint4*)(feat + i8 + 4);
      *(uint4*)(F + i8) = cvt8(a, b);
    }
    return;
  }
  int rb = bid - cvt_blocks;
  if (rb < 288) {   // raw frags: [slot 0|1][k][ks*2+ct][lane][j]
    int e = rb * 256 + tid;
    int slot = e / 36864, r = e % 36864;
    int k = r >> 12, rr = r & 4095;
    int frag = rr >> 9, lane = (rr >> 3) & 63, j = rr & 7;
    int ks = frag >> 1, ct = frag & 1;
    int cin = ks * 16 + (lane >> 5) * 8 + j;
    int cout = ct * 32 + (lane & 31);
    const float* src = slot ? w2 : w1;
    wf[e] = f2bf(src[k * 4096 + cin * 64 + cout]);
    return;
  }
  for (int i = tid; i < 4 * STG; i += 256) st[i] = 0.f;
  if (tid < 32) ((u32*)zr)[tid] = 0u;   // shared 128 B zero row
}

__device__ __forceinline__ void bn_from_replicas(const float* stp, const float* g,
                                                 const float* b, int c,
                                                 float* sc, float* sh) {
  float s = 0.f, q = 0.f;
#pragma unroll
  for (int r = 0; r < NREP; ++r) {
    s += stp[r * 128 + c];
    q += stp[r * 128 + 64 + c];
  }
  const float invn = 1.0f / (float)NVOX;
  float mean = s * invn;
  float var = q * invn - mean * mean;
  float sca = g[c] * rsqrtf(var + 1e-5f);
  *sc = sca;
  *sh = b[c] - mean * sca;
}

// fold both BN stages into both second-conv weights (one dispatch, 360 blocks)
__global__ void wscale2(const float* __restrict__ wA, float* __restrict__ stpA,
                        const float* __restrict__ gA, const float* __restrict__ bA,
                        u16* __restrict__ dA,
                        const float* __restrict__ wB, float* __restrict__ stpB,
                        const float* __restrict__ gB, const float* __restrict__ bB,
                        u16* __restrict__ dB) {
  __shared__ float sc[64], sh[64];
  const int tid = threadIdx.x;
  const bool hB = (blockIdx.x >= 180);
  const float* wraw = hB ? wB : wA;
  float* stp = hB ? stpB : stpA;
  const float* g = hB ? gB : gA;
  const float* b = hB ? bB : bA;
  u16* dst = hB ? dB : dA;
  const int blk = hB ? blockIdx.x - 180 : blockIdx.x;
  if (tid < 64) {
    float a, h;
    bn_from_replicas(stp, g, b, tid, &a, &h);
    sc[tid] = a; sh[tid] = h;
    if (blk == 0) { stp[NREP * 128 + tid] = a; stp[NREP * 128 + 64 + tid] = h; }
  }
  __syncthreads();
  int e = blk * 256 + tid;   // [0, 46080)
  int k = e / 5120, r = e % 5120;
  int frag = r >> 9, lane = (r >> 3) & 63, j = r & 7;
  int ks = frag >> 1, ct = frag & 1;
  int cout = ct * 32 + (lane & 31);
  u16 val = 0;
  if (ks < 4) {
    int cin = ks * 16 + (lane >> 5) * 8 + j;
    val = f2bf(sc[cin] * wraw[k * 4096 + cin * 64 + cout]);
  } else if (((lane >> 5) == 0) && j == 0) {
    float acc = 0.f;
    for (int c = 0; c < 64; ++c) acc += sh[c] * wraw[k * 4096 + c * 64 + cout];
    val = f2bf(acc);
  }
  dst[e] = val;
}

// both output-BN affines in one tiny dispatch (fallback tiers)
__global__ void finalize2(float* __restrict__ stA, const float* __restrict__ gA,
                          const float* __restrict__ bA, float* __restrict__ stB,
                          const float* __restrict__ gB, const float* __restrict__ bB) {
  int t = threadIdx.x;
  float* stp = (t < 64) ? stA : stB;
  const float* g = (t < 64) ? gA : gB;
  const float* b = (t < 64) ? bA : bB;
  int c = t & 63;
  if (t < 128) {
    float a, h;
    bn_from_replicas(stp, g, b, c, &a, &h);
    stp[NREP * 128 + c] = a;
    stp[NREP * 128 + 64 + c] = h;
  }
}

// io (fp32, in place) = affB(io) + affD(y3 bf16)   (fallback tiers)
__global__ void final_add(const u16* __restrict__ y3, float* io,
                          const float* __restrict__ affB, const float* __restrict__ affD) {
  int i8 = (blockIdx.x * 256 + threadIdx.x) * 8;
  if (i8 < NVOX * 64) {
    float a[8];
    *(float4*)&a[0] = *(const float4*)(io + i8);
    *(float4*)&a[4] = *(const float4*)(io + i8 + 4);
    uint4 vd = *(const uint4*)(y3 + i8);
    const u16* pd = (const u16*)&vd;
    int cb = i8 & 63;
    float o[8];
#pragma unroll
    for (int j = 0; j < 8; ++j) {
      int c = cb + j;
      o[j] = fmaf(a[j], affB[c], affB[64 + c]) + fmaf(bf2f(pd[j]), affD[c], affD[64 + c]);
    }
    *(float4*)(io + i8) = *(const float4*)&o[0];
    *(float4*)(io + i8 + 4) = *(const float4*)&o[4];
  }
}

// fused tier: finalize2 + final_add merged (affines computed per-block in LDS)
__global__ void final_add2(const u16* __restrict__ y3, float* io,
                           float* __restrict__ stB, const float* __restrict__ gB,
                           const float* __restrict__ bB,
                           float* __restrict__ stD, const float* __restrict__ gD,
                           const float* __restrict__ bD) {
  __shared__ float aff[4][64];   // [B scale][B shift][D scale][D shift]
  const int t = threadIdx.x;
  if (t < 128) {
    float a, h;
    if (t < 64) { bn_from_replicas(stB, gB, bB, t, &a, &h); aff[0][t] = a; aff[1][t] = h; }
    else { int c = t - 64; bn_from_replicas(stD, gD, bD, c, &a, &h); aff[2][c] = a; aff[3][c] = h; }
  }
  __syncthreads();
  int i8 = (blockIdx.x * 256 + t) * 8;
  if (i8 < NVOX * 64) {
    float a[8];
    *(float4*)&a[0] = *(const float4*)(io + i8);
    *(float4*)&a[4] = *(const float4*)(io + i8 + 4);
    uint4 vd = *(const uint4*)(y3 + i8);
    const u16* pd = (const u16*)&vd;
    int cb = i8 & 63;
    float o[8];
#pragma unroll
    for (int j = 0; j < 8; ++j) {
      int c = cb + j;
      o[j] = fmaf(a[j], aff[0][c], aff[1][c]) + fmaf(bf2f(pd[j]), aff[2][c], aff[3][c]);
    }
    *(float4*)(io + i8) = *(const float4*)&o[0];
    *(float4*)(io + i8 + 4) = *(const float4*)&o[4];
  }
}

extern "C" void kernel_launch(void* const* d_in, const int* in_sizes, int n_in,
                              void* d_out, int out_size, void* d_ws, size_t ws_size,
                              hipStream_t stream) {
  const float* feat = (const float*)d_in[0];
  const float* w1 = (const float*)d_in[1];
  const float* w1_2 = (const float*)d_in[2];
  const float* w2 = (const float*)d_in[3];
  const float* w3 = (const float*)d_in[4];
  const float* g0 = (const float*)d_in[5];
  const float* b0 = (const float*)d_in[6];
  const float* g0_2 = (const float*)d_in[7];
  const float* b0_2 = (const float*)d_in[8];
  const float* g1 = (const float*)d_in[9];
  const float* b1 = (const float*)d_in[10];
  const float* g2 = (const float*)d_in[11];
  const float* b2 = (const float*)d_in[12];
  const int* nbr13 = (const int*)d_in[13];
  const int* nbr31 = (const int*)d_in[14];
  float* out = (float*)d_out;

  char* ws = (char*)d_ws;
  float* st = (float*)ws;                         // 4 stages x 4224 f = 67,584 B
  u16* wf = (u16*)(ws + 67584);                   // 331,776 B of fragments
  u16* s0 = wf;                                   // w1 raw      (36,864 u16)
  u16* s1 = wf + 36864;                           // w2 raw
  u16* s2 = wf + 73728;                           // w1_2 folded (46,080 u16)
  u16* s3 = wf + 119808;                          // w3 folded
  u16* zr = (u16*)(ws + 399360);                  // shared zero row, 128 B
  u16* F = (u16*)(ws + 399488);                   // feat bf16 (later Y3), 25.6 MB
  u16* A1 = F + (size_t)NVOX * 64;                // 25.6 MB
  u16* A2 = A1 + (size_t)NVOX * 64;               // 25.6 MB (fused plan only)
  const size_t base_sz = 399488;
  const size_t need_fused = base_sz + 3ull * NVOX * 64 * 2;
  const size_t need_serial = base_sz + 2ull * NVOX * 64 * 2;

  float* st0 = st, *st1 = st + STG, *st2 = st + 2 * STG, *st3 = st + 3 * STG;

  if (ws_size >= need_fused) {
    prep_all<<<6539, 256, 0, stream>>>(feat, w1, w2, wf, F, st, zr, 6250);
    // convA: conv1(F,nbr13,s0)->A1,st0  ||  conv2(F,nbr31,s1)->A2,st2
    conv_fused<0><<<2 * BPS, 256, 0, stream>>>(F, F, nbr13, nbr31, s0, s1, zr,
                                               A1, A2, st0, st2);
    wscale2<<<360, 256, 0, stream>>>(w1_2, st0, g0, b0, s2, w3, st2, g1, b1, s3);
    // convB: conv1_2(A1,nbr31,s2)->out fp32,st1  ||  conv3(A2,nbr13,s3)->F bf16,st3
    conv_fused<1><<<2 * BPS, 256, 0, stream>>>(A1, A2, nbr31, nbr13, s2, s3, zr,
                                               out, F, st1, st3);
    final_add2<<<6250, 256, 0, stream>>>(F, out, st1, g0_2, b0_2, st3, g2, b2);
  } else if (ws_size >= need_serial) {
    prep_all<<<6539, 256, 0, stream>>>(feat, w1, w2, wf, F, st, zr, 6250);
    conv_k<false, false, 0><<<NBLK, 256, 0, stream>>>(F, nbr13, s0, A1, st0, nullptr, nullptr, nullptr);
    wscale2<<<180, 256, 0, stream>>>(w1_2, st0, g0, b0, s2, w3, st2, g1, b1, s3);  // only half used
    conv_k<false, true, 3><<<NBLK, 256, 0, stream>>>(A1, nbr31, s2, out, st1, nullptr, nullptr, nullptr);
    conv_k<false, false, 0><<<NBLK, 256, 0, stream>>>(F, nbr31, s1, A1, st2, nullptr, nullptr, nullptr);
    wscale2<<<360, 256, 0, stream>>>(w1_2, st0, g0, b0, s2, w3, st2, g1, b1, s3);
    conv_k<false, true, 0><<<NBLK, 256, 0, stream>>>(A1, nbr13, s3, F, st3, nullptr, nullptr, nullptr);
    finalize2<<<1, 128, 0, stream>>>(st1, g0_2, b0_2, st3, g2, b2);
    final_add<<<6250, 256, 0, stream>>>(F, out, st1 + NREP * 128, st3 + NREP * 128);
  } else {
    // minimal-ws: recompute path (round-6 small)
    u16* Az = F;
    prep_all<<<289, 256, 0, stream>>>(feat, w1, w2, wf, nullptr, st, zr, 0);
    conv_k<true, false, 0><<<NBLK, 256, 0, stream>>>(feat, nbr13, s0, Az, st0, nullptr, nullptr, nullptr);
    wscale2<<<180, 256, 0, stream>>>(w1_2, st0, g0, b0, s2, w3, st2, g1, b1, s3);
    conv_k<false, true, 3><<<NBLK, 256, 0, stream>>>(Az, nbr31, s2, out, st1, nullptr, nullptr, nullptr);
    finalize2<<<1, 128, 0, stream>>>(st1, g0_2, b0_2, st3, g2, b2);
    conv_k<true, false, 0><<<NBLK, 256, 0, stream>>>(feat, nbr31, s1, Az, st2, nullptr, nullptr, nullptr);
    wscale2<<<360, 256, 0, stream>>>(w1_2, st0, g0, b0, s2, w3, st2, g1, b1, s3);
    conv_k<false, true, 1><<<NBLK, 256, 0, stream>>>(Az, nbr13, s3, nullptr, st3, nullptr, nullptr, nullptr);
    finalize2<<<1, 128, 0, stream>>>(st1, g0_2, b0_2, st3, g2, b2);
    conv_k<false, true, 2><<<NBLK, 256, 0, stream>>>(Az, nbr13, s3, out, nullptr, out,
                                                     st3 + NREP * 128, st1 + NREP * 128);
  }
}

// Round 4
// 280.228 us; speedup vs baseline: 2.4508x; 2.4508x over previous
//
#include <hip/hip_runtime.h>

#define NVOX 200000
#define TM 128
#define NBLK 1563   // ceil(200000/128)
#define NREP 32     // stats-accumulator replicas
#define STG 4224    // floats per stage: 32*128 replicas + 64 scale + 64 shift

typedef unsigned short u16;
typedef unsigned int u32;
typedef __bf16 bf16x8 __attribute__((ext_vector_type(8)));
typedef float f32x16 __attribute__((ext_vector_type(16)));

__device__ __forceinline__ float bf2f(u16 h) { return __uint_as_float(((u32)h) << 16); }
__device__ __forceinline__ u16 f2bf(float x) {
  u32 u = __float_as_uint(x);
  u32 r = u + 0x7fffu + ((u >> 16) & 1u);   // RNE
  return (u16)(r >> 16);
}
__device__ __forceinline__ uint4 cvt8(uint4 a, uint4 b) {
  const float* fa = (const float*)&a;
  const float* fb = (const float*)&b;
  uint4 r;
  u16* q = (u16*)&r;
#pragma unroll
  for (int j = 0; j < 4; ++j) { q[j] = f2bf(fa[j]); q[4 + j] = f2bf(fb[j]); }
  return r;
}
__device__ __forceinline__ int popnext(u32& m) {
  int k = __builtin_ctz(m); m &= m - 1; return k;
}

// ---------------------------------------------------------------------------
// Fused conv pair, round 10: round-0 shell + live-mask pipelined tap loop.
//  - 9 upfront ballots -> wave-uniform live-tap bitmask (SGPR)
//  - dynamic loop over live taps, 2x-unrolled X/Y ping-pong: gathers of the
//    NEXT live tap issue before the MFMAs of the current one (depth-1 SWP)
//  - tap work identical to round 0 (ballot skip preserved)
//  - neighbor ids re-loaded per live tap from L1-hot nbr row (no dynamic
//    register-array indexing -> no scratch)
//  - missing rows: pointer-select to shared zero row (no exec-mask zero fill)
//  - epilogue identical to round 0 (LDS bounce, coalesced stores)
// PHASE 0 (convA): raw weights; both streams -> bf16 + stats.
// PHASE 1 (convB): folded weights (+bias K-step); stream A -> fp32 out + stats,
//                  stream B -> bf16 + stats.
// ---------------------------------------------------------------------------
template <int PHASE>
__global__ __launch_bounds__(256, 4)
void conv_fused(const u16* __restrict__ inA, const u16* __restrict__ inB,
                const int* __restrict__ nbrA, const int* __restrict__ nbrB,
                const u16* __restrict__ wfA, const u16* __restrict__ wfB,
                const u16* __restrict__ zrow,
                void* yA, void* yB, float* __restrict__ stA, float* __restrict__ stB) {
  __shared__ __align__(16) float fb4[64 * 68];   // 17,408 B (u16 alias [64][72])
  __shared__ float sred[4][128];

  const int tid = threadIdx.x;
  const int bid = blockIdx.x;
  const bool hB = (bid >= NBLK);
  const int blk = hB ? bid - NBLK : bid;
  const u16* f = hB ? inB : inA;
  const int* nbr = hB ? nbrB : nbrA;
  const u16* wf = hB ? wfB : wfA;
  float* st = hB ? stB : stA;

  const int wv = tid >> 6;
  const int lane = tid & 63;
  const int lrow = lane & 31;
  const int lq = lane >> 5;
  const int base = blk * TM;
  const int gr = base + wv * 32 + lrow;
  const bool okrow = (gr < NVOX);
  const int* nrow = nbr + (size_t)(okrow ? gr : 0) * 9;

  constexpr bool FOLDED = (PHASE == 1);
  constexpr int KSTRIDE = FOLDED ? 5120 : 4096;

  // ---- ballot phase: build wave-uniform live-tap mask --------------------
  u32 live = 1u << 4;   // center tap always live
  {
    int idt[9];
#pragma unroll
    for (int j = 0; j < 9; ++j) idt[j] = okrow ? nrow[j] : NVOX;
#pragma unroll
    for (int j = 0; j < 9; ++j)
      if (j != 4 && __ballot(idt[j] < NVOX) != 0ull) live |= 1u << j;
  }

  f32x16 acc0 = {0.f, 0.f, 0.f, 0.f, 0.f, 0.f, 0.f, 0.f,
                 0.f, 0.f, 0.f, 0.f, 0.f, 0.f, 0.f, 0.f};
  f32x16 acc1 = acc0;

  auto LDID = [&](int k) { return okrow ? nrow[k] : NVOX; };
  auto G = [&](uint4 (&d)[4], int id) {
    const u16* p = (id < NVOX) ? (f + (size_t)id * 64) : zrow;
    p += lq * 8;
    d[0] = *(const uint4*)(p);
    d[1] = *(const uint4*)(p + 16);
    d[2] = *(const uint4*)(p + 32);
    d[3] = *(const uint4*)(p + 48);
  };
  auto MMA = [&](const uint4 (&s)[4], int k, int id) {
    const u16* wb = wf + k * KSTRIDE;
#pragma unroll
    for (int ksi = 0; ksi < 4; ++ksi) {
      bf16x8 a = __builtin_bit_cast(bf16x8, s[ksi]);
      bf16x8 b0 = __builtin_bit_cast(bf16x8, *(const uint4*)(wb + (ksi * 2) * 512 + lane * 8));
      bf16x8 b1 = __builtin_bit_cast(bf16x8, *(const uint4*)(wb + (ksi * 2 + 1) * 512 + lane * 8));
      acc0 = __builtin_amdgcn_mfma_f32_32x32x16_bf16(a, b0, acc0, 0, 0, 0);
      acc1 = __builtin_amdgcn_mfma_f32_32x32x16_bf16(a, b1, acc1, 0, 0, 0);
    }
    if constexpr (FOLDED) {   // bias channel: A = 1[exists] at (lq=0, j=0)
      uint4 a4 = make_uint4(0u, 0u, 0u, 0u);
      if (lq == 0 && id < NVOX) ((u16*)&a4)[0] = 0x3F80u;
      bf16x8 a = __builtin_bit_cast(bf16x8, a4);
      bf16x8 b0 = __builtin_bit_cast(bf16x8, *(const uint4*)(wb + 8 * 512 + lane * 8));
      bf16x8 b1 = __builtin_bit_cast(bf16x8, *(const uint4*)(wb + 9 * 512 + lane * 8));
      acc0 = __builtin_amdgcn_mfma_f32_32x32x16_bf16(a, b0, acc0, 0, 0, 0);
      acc1 = __builtin_amdgcn_mfma_f32_32x32x16_bf16(a, b1, acc1, 0, 0, 0);
    }
  };

  // ---- pipelined dynamic tap loop (2x-unrolled X/Y ping-pong) ------------
  {
    uint4 X[4], Y[4];
    int k0 = popnext(live);
    int id0 = LDID(k0);
    G(X, id0);
    while (true) {
      int k1 = -1, id1 = NVOX;
      if (live) { k1 = popnext(live); id1 = LDID(k1); G(Y, id1); }
      MMA(X, k0, id0);
      if (k1 < 0) break;
      int k2 = -1, id2 = NVOX;
      if (live) { k2 = popnext(live); id2 = LDID(k2); G(X, id2); }
      MMA(Y, k1, id1);
      if (k2 < 0) break;
      k0 = k2; id0 = id2;
    }
  }

  // ---- epilogue (identical to round 0) -----------------------------------
  // C/D (32x32): col = lane&31, row = (reg&3) + 8*(reg>>2) + 4*(lane>>5)
  const int cc0 = lrow, cc1 = 32 + lrow;
  float s0 = 0.f, q0 = 0.f, s1 = 0.f, q1 = 0.f;
  float vout[2][16];
#pragma unroll
  for (int r = 0; r < 16; ++r) {
    float v = acc0[r]; v = v > 0.f ? v : 0.01f * v;
    s0 += v; q0 += v * v; vout[0][r] = v;
    float w = acc1[r]; w = w > 0.f ? w : 0.01f * w;
    s1 += w; q1 += w * w; vout[1][r] = w;
  }
  s0 += __shfl_xor(s0, 32); q0 += __shfl_xor(q0, 32);
  s1 += __shfl_xor(s1, 32); q1 += __shfl_xor(q1, 32);
  if (lq == 0) {   // rows >= NVOX contribute exact 0
    sred[wv][lrow] = s0; sred[wv][32 + lrow] = s1;
    sred[wv][64 + lrow] = q0; sred[wv][96 + lrow] = q1;
  }

  const bool f32out = (PHASE == 1) && !hB;
  const int trow = tid >> 3, cp = tid & 7;
  u16* bb = (u16*)fb4;
#pragma unroll
  for (int h = 0; h < 2; ++h) {
    __syncthreads();
    if ((wv >> 1) == h) {
      const int lr = 32 * (wv & 1);
#pragma unroll
      for (int r = 0; r < 16; ++r) {
        int rowD = lr + (r & 3) + 8 * (r >> 2) + 4 * lq;
        if (f32out) {
          fb4[rowD * 68 + cc0] = vout[0][r];
          fb4[rowD * 68 + cc1] = vout[1][r];
        } else {
          bb[rowD * 72 + cc0] = f2bf(vout[0][r]);
          bb[rowD * 72 + cc1] = f2bf(vout[1][r]);
        }
      }
    }
    __syncthreads();
    if (f32out) {
      float* y = (float*)yA;
#pragma unroll
      for (int it = 0; it < 2; ++it) {
        int r = it * 32 + trow, row = base + 64 * h + r;
        if (row < NVOX) {
          *(float4*)(y + (size_t)row * 64 + cp * 8) = *(const float4*)(fb4 + r * 68 + cp * 8);
          *(float4*)(y + (size_t)row * 64 + cp * 8 + 4) = *(const float4*)(fb4 + r * 68 + cp * 8 + 4);
        }
      }
    } else {
      u16* y = (u16*)(hB ? yB : yA);
#pragma unroll
      for (int it = 0; it < 2; ++it) {
        int r = it * 32 + trow, row = base + 64 * h + r;
        if (row < NVOX)
          *(uint4*)(y + (size_t)row * 64 + cp * 8) = *(const uint4*)(bb + r * 72 + cp * 8);
      }
    }
  }
  if (tid < 128) {
    int which = tid >> 6, c = tid & 63;
    float v = sred[0][which * 64 + c] + sred[1][which * 64 + c] +
              sred[2][which * 64 + c] + sred[3][which * 64 + c];
    atomicAdd(&st[(bid & (NREP - 1)) * 128 + which * 64 + c], v);
  }
}

// ---- round-6 serial conv (fallback tiers) ---------------------------------
template <bool IN_F32, bool FOLDED, int MODE>
__global__ __launch_bounds__(256, 4)
void conv_k(const void* __restrict__ fv, const int* __restrict__ nbr,
            const u16* __restrict__ wf, void* yv, float* __restrict__ st,
            float* io, const float* __restrict__ affD,
            const float* __restrict__ affB) {
  __shared__ __align__(16) float fb[128 * 68];
  __shared__ float sred[4][128];

  const int tid = threadIdx.x;
  const int wv = tid >> 6;
  const int lane = tid & 63;
  const int lrow = lane & 31;
  const int lq = lane >> 5;
  const int base = blockIdx.x * TM;
  const int gr = base + wv * 32 + lrow;

  int ids[9];
#pragma unroll
  for (int j = 0; j < 9; ++j) ids[j] = (gr < NVOX) ? nbr[gr * 9 + j] : NVOX;

  f32x16 acc0 = {0.f, 0.f, 0.f, 0.f, 0.f, 0.f, 0.f, 0.f,
                 0.f, 0.f, 0.f, 0.f, 0.f, 0.f, 0.f, 0.f};
  f32x16 acc1 = acc0;
  constexpr int KSTRIDE = FOLDED ? 5120 : 4096;

#pragma unroll
  for (int k = 0; k < 9; ++k) {
    if (k != 4) {
      if (__ballot(ids[k] < NVOX) == 0ull) continue;
    }
    const int id = ids[k];
    const bool ok = id < NVOX;
    uint4 af[4];
    if constexpr (IN_F32) {
      const float* p = (const float*)fv + (size_t)id * 64 + lq * 8;
#pragma unroll
      for (int ksi = 0; ksi < 4; ++ksi) {
        uint4 v0 = make_uint4(0u, 0u, 0u, 0u), v1 = v0;
        if (ok) { v0 = *(const uint4*)(p + ksi * 16); v1 = *(const uint4*)(p + ksi * 16 + 4); }
        af[ksi] = cvt8(v0, v1);
      }
    } else {
      const u16* p = (const u16*)fv + (size_t)id * 64 + lq * 8;
#pragma unroll
      for (int ksi = 0; ksi < 4; ++ksi) {
        uint4 v = make_uint4(0u, 0u, 0u, 0u);
        if (ok) v = *(const uint4*)(p + ksi * 16);
        af[ksi] = v;
      }
    }
    const u16* wb = wf + k * KSTRIDE;
#pragma unroll
    for (int ksi = 0; ksi < 4; ++ksi) {
      bf16x8 a = __builtin_bit_cast(bf16x8, af[ksi]);
      bf16x8 b0 = __builtin_bit_cast(bf16x8, *(const uint4*)(wb + (ksi * 2) * 512 + lane * 8));
      bf16x8 b1 = __builtin_bit_cast(bf16x8, *(const uint4*)(wb + (ksi * 2 + 1) * 512 + lane * 8));
      acc0 = __builtin_amdgcn_mfma_f32_32x32x16_bf16(a, b0, acc0, 0, 0, 0);
      acc1 = __builtin_amdgcn_mfma_f32_32x32x16_bf16(a, b1, acc1, 0, 0, 0);
    }
    if constexpr (FOLDED) {
      uint4 a4 = make_uint4(0u, 0u, 0u, 0u);
      if (lq == 0 && ok) ((u16*)&a4)[0] = 0x3F80u;
      bf16x8 a = __builtin_bit_cast(bf16x8, a4);
      bf16x8 b0 = __builtin_bit_cast(bf16x8, *(const uint4*)(wb + 8 * 512 + lane * 8));
      bf16x8 b1 = __builtin_bit_cast(bf16x8, *(const uint4*)(wb + 9 * 512 + lane * 8));
      acc0 = __builtin_amdgcn_mfma_f32_32x32x16_bf16(a, b0, acc0, 0, 0, 0);
      acc1 = __builtin_amdgcn_mfma_f32_32x32x16_bf16(a, b1, acc1, 0, 0, 0);
    }
  }

  const int cc0 = lrow, cc1 = 32 + lrow;
  float aD0 = 0.f, aD1 = 0.f, hD0 = 0.f, hD1 = 0.f;
  if constexpr (MODE == 2) {
    aD0 = affD[cc0]; hD0 = affD[64 + cc0];
    aD1 = affD[cc1]; hD1 = affD[64 + cc1];
  }
  float s0 = 0.f, q0 = 0.f, s1 = 0.f, q1 = 0.f;
  float vout[2][16];
#pragma unroll
  for (int r = 0; r < 16; ++r) {
    float v = acc0[r]; v = v > 0.f ? v : 0.01f * v;
    s0 += v; q0 += v * v; vout[0][r] = v;
    float w = acc1[r]; w = w > 0.f ? w : 0.01f * w;
    s1 += w; q1 += w * w; vout[1][r] = w;
  }
  if constexpr (MODE != 2) {
    s0 += __shfl_xor(s0, 32); q0 += __shfl_xor(q0, 32);
    s1 += __shfl_xor(s1, 32); q1 += __shfl_xor(q1, 32);
    if (lq == 0) {
      sred[wv][lrow] = s0; sred[wv][32 + lrow] = s1;
      sred[wv][64 + lrow] = q0; sred[wv][96 + lrow] = q1;
    }
  }
  if constexpr (MODE == 0) {
    u16* bb = (u16*)fb;
#pragma unroll
    for (int r = 0; r < 16; ++r) {
      int rowD = 32 * wv + (r & 3) + 8 * (r >> 2) + 4 * lq;
      bb[rowD * 72 + cc0] = f2bf(vout[0][r]);
      bb[rowD * 72 + cc1] = f2bf(vout[1][r]);
    }
  } else if constexpr (MODE == 2 || MODE == 3) {
#pragma unroll
    for (int r = 0; r < 16; ++r) {
      int rowD = 32 * wv + (r & 3) + 8 * (r >> 2) + 4 * lq;
      float v0 = vout[0][r], v1 = vout[1][r];
      if constexpr (MODE == 2) { v0 = fmaf(v0, aD0, hD0); v1 = fmaf(v1, aD1, hD1); }
      fb[rowD * 68 + cc0] = v0;
      fb[rowD * 68 + cc1] = v1;
    }
  }
  __syncthreads();

  const int trow = tid >> 3, cp = tid & 7;
  if constexpr (MODE == 0) {
    u16* y = (u16*)yv;
    const u16* bb = (const u16*)fb;
#pragma unroll
    for (int it = 0; it < 4; ++it) {
      int r = it * 32 + trow, row = base + r;
      if (row < NVOX)
        *(uint4*)(y + (size_t)row * 64 + cp * 8) = *(const uint4*)(bb + r * 72 + cp * 8);
    }
  }
  if constexpr (MODE == 3) {
    float* y = (float*)yv;
#pragma unroll
    for (int it = 0; it < 4; ++it) {
      int r = it * 32 + trow, row = base + r;
      if (row < NVOX) {
        *(float4*)(y + (size_t)row * 64 + cp * 8) = *(const float4*)(fb + r * 68 + cp * 8);
        *(float4*)(y + (size_t)row * 64 + cp * 8 + 4) = *(const float4*)(fb + r * 68 + cp * 8 + 4);
      }
    }
  }
  if constexpr (MODE == 2) {
    float* y = (float*)yv;
#pragma unroll
    for (int it = 0; it < 4; ++it) {
      int r = it * 32 + trow, row = base + r;
      if (row < NVOX) {
        float t[8], p[8], o[8];
        *(float4*)&t[0] = *(const float4*)(fb + r * 68 + cp * 8);
        *(float4*)&t[4] = *(const float4*)(fb + r * 68 + cp * 8 + 4);
        *(float4*)&p[0] = *(const float4*)(io + (size_t)row * 64 + cp * 8);
        *(float4*)&p[4] = *(const float4*)(io + (size_t)row * 64 + cp * 8 + 4);
#pragma unroll
        for (int j = 0; j < 8; ++j) {
          int c = cp * 8 + j;
          o[j] = t[j] + fmaf(p[j], affB[c], affB[64 + c]);
        }
        *(float4*)(y + (size_t)row * 64 + cp * 8) = *(const float4*)&o[0];
        *(float4*)(y + (size_t)row * 64 + cp * 8 + 4) = *(const float4*)&o[4];
      }
    }
  }
  if constexpr (MODE != 2) {
    if (tid < 128) {
      int which = tid >> 6, c = tid & 63;
      float v = sred[0][which * 64 + c] + sred[1][which * 64 + c] +
                sred[2][which * 64 + c] + sred[3][which * 64 + c];
      atomicAdd(&st[(blockIdx.x & (NREP - 1)) * 128 + which * 64 + c], v);
    }
  }
}

// prep: feat fp32 -> bf16, raw weight fragments (w1, w2), zero stats + zero row
__global__ void prep_all(const float* __restrict__ feat, const float* __restrict__ w1,
                         const float* __restrict__ w2, u16* __restrict__ wf,
                         u16* __restrict__ F, float* __restrict__ st,
                         u16* __restrict__ zr, int cvt_blocks) {
  const int bid = blockIdx.x, tid = threadIdx.x;
  if (bid < cvt_blocks) {
    int i8 = (bid * 256 + tid) * 8;
    if (i8 < NVOX * 64) {
      uint4 a = *(const uint4*)(feat + i8);
      uint4 b = *(const uint4*)(feat + i8 + 4);
      *(uint4*)(F + i8) = cvt8(a, b);
    }
    return;
  }
  int rb = bid - cvt_blocks;
  if (rb < 288) {   // raw frags: [slot 0|1][k][ks*2+ct][lane][j]
    int e = rb * 256 + tid;
    int slot = e / 36864, r = e % 36864;
    int k = r >> 12, rr = r & 4095;
    int frag = rr >> 9, lane = (rr >> 3) & 63, j = rr & 7;
    int ks = frag >> 1, ct = frag & 1;
    int cin = ks * 16 + (lane >> 5) * 8 + j;
    int cout = ct * 32 + (lane & 31);
    const float* src = slot ? w2 : w1;
    wf[e] = f2bf(src[k * 4096 + cin * 64 + cout]);
    return;
  }
  for (int i = tid; i < 4 * STG; i += 256) st[i] = 0.f;
  if (tid < 32) ((u32*)zr)[tid] = 0u;   // shared 128 B zero row
}

__device__ __forceinline__ void bn_from_replicas(const float* stp, const float* g,
                                                 const float* b, int c,
                                                 float* sc, float* sh) {
  float s = 0.f, q = 0.f;
#pragma unroll
  for (int r = 0; r < NREP; ++r) {
    s += stp[r * 128 + c];
    q += stp[r * 128 + 64 + c];
  }
  const float invn = 1.0f / (float)NVOX;
  float mean = s * invn;
  float var = q * invn - mean * mean;
  float sca = g[c] * rsqrtf(var + 1e-5f);
  *sc = sca;
  *sh = b[c] - mean * sca;
}

// fold both BN stages into both second-conv weights (one dispatch, 360 blocks)
__global__ void wscale2(const float* __restrict__ wA, float* __restrict__ stpA,
                        const float* __restrict__ gA, const float* __restrict__ bA,
                        u16* __restrict__ dA,
                        const float* __restrict__ wB, float* __restrict__ stpB,
                        const float* __restrict__ gB, const float* __restrict__ bB,
                        u16* __restrict__ dB) {
  __shared__ float sc[64], sh[64];
  const int tid = threadIdx.x;
  const bool hB = (blockIdx.x >= 180);
  const float* wraw = hB ? wB : wA;
  float* stp = hB ? stpB : stpA;
  const float* g = hB ? gB : gA;
  const float* b = hB ? bB : bA;
  u16* dst = hB ? dB : dA;
  const int blk = hB ? blockIdx.x - 180 : blockIdx.x;
  if (tid < 64) {
    float a, h;
    bn_from_replicas(stp, g, b, tid, &a, &h);
    sc[tid] = a; sh[tid] = h;
    if (blk == 0) { stp[NREP * 128 + tid] = a; stp[NREP * 128 + 64 + tid] = h; }
  }
  __syncthreads();
  int e = blk * 256 + tid;   // [0, 46080)
  int k = e / 5120, r = e % 5120;
  int frag = r >> 9, lane = (r >> 3) & 63, j = r & 7;
  int ks = frag >> 1, ct = frag & 1;
  int cout = ct * 32 + (lane & 31);
  u16 val = 0;
  if (ks < 4) {
    int cin = ks * 16 + (lane >> 5) * 8 + j;
    val = f2bf(sc[cin] * wraw[k * 4096 + cin * 64 + cout]);
  } else if (((lane >> 5) == 0) && j == 0) {
    float acc = 0.f;
    for (int c = 0; c < 64; ++c) acc += sh[c] * wraw[k * 4096 + c * 64 + cout];
    val = f2bf(acc);
  }
  dst[e] = val;
}

// both output-BN affines in one tiny dispatch (fallback tiers)
__global__ void finalize2(float* __restrict__ stA, const float* __restrict__ gA,
                          const float* __restrict__ bA, float* __restrict__ stB,
                          const float* __restrict__ gB, const float* __restrict__ bB) {
  int t = threadIdx.x;
  float* stp = (t < 64) ? stA : stB;
  const float* g = (t < 64) ? gA : gB;
  const float* b = (t < 64) ? bA : bB;
  int c = t & 63;
  if (t < 128) {
    float a, h;
    bn_from_replicas(stp, g, b, c, &a, &h);
    stp[NREP * 128 + c] = a;
    stp[NREP * 128 + 64 + c] = h;
  }
}

// io (fp32, in place) = affB(io) + affD(y3 bf16)   (fallback tiers)
__global__ void final_add(const u16* __restrict__ y3, float* io,
                          const float* __restrict__ affB, const float* __restrict__ affD) {
  int i8 = (blockIdx.x * 256 + threadIdx.x) * 8;
  if (i8 < NVOX * 64) {
    float a[8];
    *(float4*)&a[0] = *(const float4*)(io + i8);
    *(float4*)&a[4] = *(const float4*)(io + i8 + 4);
    uint4 vd = *(const uint4*)(y3 + i8);
    const u16* pd = (const u16*)&vd;
    int cb = i8 & 63;
    float o[8];
#pragma unroll
    for (int j = 0; j < 8; ++j) {
      int c = cb + j;
      o[j] = fmaf(a[j], affB[c], affB[64 + c]) + fmaf(bf2f(pd[j]), affD[c], affD[64 + c]);
    }
    *(float4*)(io + i8) = *(const float4*)&o[0];
    *(float4*)(io + i8 + 4) = *(const float4*)&o[4];
  }
}

// fused tier: finalize2 + final_add merged (affines computed per-block in LDS)
__global__ void final_add2(const u16* __restrict__ y3, float* io,
                           float* __restrict__ stB, const float* __restrict__ gB,
                           const float* __restrict__ bB,
                           float* __restrict__ stD, const float* __restrict__ gD,
                           const float* __restrict__ bD) {
  __shared__ float aff[4][64];   // [B scale][B shift][D scale][D shift]
  const int t = threadIdx.x;
  if (t < 128) {
    float a, h;
    if (t < 64) { bn_from_replicas(stB, gB, bB, t, &a, &h); aff[0][t] = a; aff[1][t] = h; }
    else { int c = t - 64; bn_from_replicas(stD, gD, bD, c, &a, &h); aff[2][c] = a; aff[3][c] = h; }
  }
  __syncthreads();
  int i8 = (blockIdx.x * 256 + t) * 8;
  if (i8 < NVOX * 64) {
    float a[8];
    *(float4*)&a[0] = *(const float4*)(io + i8);
    *(float4*)&a[4] = *(const float4*)(io + i8 + 4);
    uint4 vd = *(const uint4*)(y3 + i8);
    const u16* pd = (const u16*)&vd;
    int cb = i8 & 63;
    float o[8];
#pragma unroll
    for (int j = 0; j < 8; ++j) {
      int c = cb + j;
      o[j] = fmaf(a[j], aff[0][c], aff[1][c]) + fmaf(bf2f(pd[j]), aff[2][c], aff[3][c]);
    }
    *(float4*)(io + i8) = *(const float4*)&o[0];
    *(float4*)(io + i8 + 4) = *(const float4*)&o[4];
  }
}

extern "C" void kernel_launch(void* const* d_in, const int* in_sizes, int n_in,
                              void* d_out, int out_size, void* d_ws, size_t ws_size,
                              hipStream_t stream) {
  const float* feat = (const float*)d_in[0];
  const float* w1 = (const float*)d_in[1];
  const float* w1_2 = (const float*)d_in[2];
  const float* w2 = (const float*)d_in[3];
  const float* w3 = (const float*)d_in[4];
  const float* g0 = (const float*)d_in[5];
  const float* b0 = (const float*)d_in[6];
  const float* g0_2 = (const float*)d_in[7];
  const float* b0_2 = (const float*)d_in[8];
  const float* g1 = (const float*)d_in[9];
  const float* b1 = (const float*)d_in[10];
  const float* g2 = (const float*)d_in[11];
  const float* b2 = (const float*)d_in[12];
  const int* nbr13 = (const int*)d_in[13];
  const int* nbr31 = (const int*)d_in[14];
  float* out = (float*)d_out;

  char* ws = (char*)d_ws;
  float* st = (float*)ws;                         // 4 stages x 4224 f = 67,584 B
  u16* wf = (u16*)(ws + 67584);                   // 331,776 B of fragments
  u16* s0 = wf;                                   // w1 raw      (36,864 u16)
  u16* s1 = wf + 36864;                           // w2 raw
  u16* s2 = wf + 73728;                           // w1_2 folded (46,080 u16)
  u16* s3 = wf + 119808;                          // w3 folded
  u16* zr = (u16*)(ws + 399360);                  // shared zero row, 128 B
  u16* F = (u16*)(ws + 399488);                   // feat bf16 (later Y3), 25.6 MB
  u16* A1 = F + (size_t)NVOX * 64;                // 25.6 MB
  u16* A2 = A1 + (size_t)NVOX * 64;               // 25.6 MB (fused plan only)
  const size_t base_sz = 399488;
  const size_t need_fused = base_sz + 3ull * NVOX * 64 * 2;
  const size_t need_serial = base_sz + 2ull * NVOX * 64 * 2;

  float* st0 = st, *st1 = st + STG, *st2 = st + 2 * STG, *st3 = st + 3 * STG;

  if (ws_size >= need_fused) {
    prep_all<<<6539, 256, 0, stream>>>(feat, w1, w2, wf, F, st, zr, 6250);
    // convA: conv1(F,nbr13,s0)->A1,st0  ||  conv2(F,nbr31,s1)->A2,st2
    conv_fused<0><<<2 * NBLK, 256, 0, stream>>>(F, F, nbr13, nbr31, s0, s1, zr,
                                                A1, A2, st0, st2);
    wscale2<<<360, 256, 0, stream>>>(w1_2, st0, g0, b0, s2, w3, st2, g1, b1, s3);
    // convB: conv1_2(A1,nbr31,s2)->out fp32,st1  ||  conv3(A2,nbr13,s3)->F bf16,st3
    conv_fused<1><<<2 * NBLK, 256, 0, stream>>>(A1, A2, nbr31, nbr13, s2, s3, zr,
                                                out, F, st1, st3);
    final_add2<<<6250, 256, 0, stream>>>(F, out, st1, g0_2, b0_2, st3, g2, b2);
  } else if (ws_size >= need_serial) {
    prep_all<<<6539, 256, 0, stream>>>(feat, w1, w2, wf, F, st, zr, 6250);
    conv_k<false, false, 0><<<NBLK, 256, 0, stream>>>(F, nbr13, s0, A1, st0, nullptr, nullptr, nullptr);
    wscale2<<<180, 256, 0, stream>>>(w1_2, st0, g0, b0, s2, w3, st2, g1, b1, s3);  // only half used
    conv_k<false, true, 3><<<NBLK, 256, 0, stream>>>(A1, nbr31, s2, out, st1, nullptr, nullptr, nullptr);
    conv_k<false, false, 0><<<NBLK, 256, 0, stream>>>(F, nbr31, s1, A1, st2, nullptr, nullptr, nullptr);
    wscale2<<<360, 256, 0, stream>>>(w1_2, st0, g0, b0, s2, w3, st2, g1, b1, s3);
    conv_k<false, true, 0><<<NBLK, 256, 0, stream>>>(A1, nbr13, s3, F, st3, nullptr, nullptr, nullptr);
    finalize2<<<1, 128, 0, stream>>>(st1, g0_2, b0_2, st3, g2, b2);
    final_add<<<6250, 256, 0, stream>>>(F, out, st1 + NREP * 128, st3 + NREP * 128);
  } else {
    // minimal-ws: recompute path (round-6 small)
    u16* Az = F;
    prep_all<<<289, 256, 0, stream>>>(feat, w1, w2, wf, nullptr, st, zr, 0);
    conv_k<true, false, 0><<<NBLK, 256, 0, stream>>>(feat, nbr13, s0, Az, st0, nullptr, nullptr, nullptr);
    wscale2<<<180, 256, 0, stream>>>(w1_2, st0, g0, b0, s2, w3, st2, g1, b1, s3);
    conv_k<false, true, 3><<<NBLK, 256, 0, stream>>>(Az, nbr31, s2, out, st1, nullptr, nullptr, nullptr);
    finalize2<<<1, 128, 0, stream>>>(st1, g0_2, b0_2, st3, g2, b2);
    conv_k<true, false, 0><<<NBLK, 256, 0, stream>>>(feat, nbr31, s1, Az, st2, nullptr, nullptr, nullptr);
    wscale2<<<360, 256, 0, stream>>>(w1_2, st0, g0, b0, s2, w3, st2, g1, b1, s3);
    conv_k<false, true, 1><<<NBLK, 256, 0, stream>>>(Az, nbr13, s3, nullptr, st3, nullptr, nullptr, nullptr);
    finalize2<<<1, 128, 0, stream>>>(st1, g0_2, b0_2, st3, g2, b2);
    conv_k<false, true, 2><<<NBLK, 256, 0, stream>>>(Az, nbr13, s3, out, nullptr, out,
                                                     st3 + NREP * 128, st1 + NREP * 128);
  }
}

// Round 5
// 275.693 us; speedup vs baseline: 2.4911x; 1.0164x over previous
//
#include <hip/hip_runtime.h>

#define NVOX 200000
#define TM 128
#define NBLK 1563   // ceil(200000/128)  (fallback tiers)
#define NBLK8 782   // ceil(200000/256)  (fused tier: 256 rows/block, 8 waves)
#define NREP 32     // stats-accumulator replicas
#define STG 4224    // floats per stage: 32*128 replicas + 64 scale + 64 shift

typedef unsigned short u16;
typedef unsigned int u32;
typedef __bf16 bf16x8 __attribute__((ext_vector_type(8)));
typedef float f32x16 __attribute__((ext_vector_type(16)));

__device__ __forceinline__ float bf2f(u16 h) { return __uint_as_float(((u32)h) << 16); }
__device__ __forceinline__ u16 f2bf(float x) {
  u32 u = __float_as_uint(x);
  u32 r = u + 0x7fffu + ((u >> 16) & 1u);   // RNE
  return (u16)(r >> 16);
}
__device__ __forceinline__ uint4 cvt8(uint4 a, uint4 b) {
  const float* fa = (const float*)&a;
  const float* fb = (const float*)&b;
  uint4 r;
  u16* q = (u16*)&r;
#pragma unroll
  for (int j = 0; j < 4; ++j) { q[j] = f2bf(fa[j]); q[4 + j] = f2bf(fb[j]); }
  return r;
}

// ---------------------------------------------------------------------------
// Fused conv pair, round 11: round-0 k-loop + LDS-resident weights.
//  - 512 threads / 8 waves / 256 rows per block; grid 2 x 782
//  - weight fragments (8 frags x 9 taps = 73.7 KB) staged to LDS once per
//    block: weight reads move off the TA/L1 path (which r0 saturated with
//    8 KB/tap/wave re-reads) onto the parallel LDS pipe, amortized 8 waves
//  - k-loop identical to round 0: static unroll, per-wave ballot skip,
//    exec-masked gathers (dead lanes fetch nothing)
//  - PHASE1 bias frags (2/tap) read from global JIT (~11 loads/wave total)
//  - epilogue: 16-row LDS bounce chunks (union'd with sred), coalesced stores
// PHASE 0 (convA): raw weights; both streams -> bf16 + stats.
// PHASE 1 (convB): folded weights (+bias K-step); stream A -> fp32 out + stats,
//                  stream B -> bf16 + stats.
// ---------------------------------------------------------------------------
template <int PHASE>
__global__ __launch_bounds__(512, 4)
void conv_fused(const u16* __restrict__ inA, const u16* __restrict__ inB,
                const int* __restrict__ nbrA, const int* __restrict__ nbrB,
                const u16* __restrict__ wfA, const u16* __restrict__ wfB,
                const u16* __restrict__ zrow,
                void* yA, void* yB, float* __restrict__ stA, float* __restrict__ stB) {
  __shared__ __align__(16) u16 wlds[9 * 4096];        // 73,728 B weight cache
  __shared__ __align__(16) float fbx[16 * 68 + 8];    // 4,384 B bounce / sred union

  const int tid = threadIdx.x;
  const int bid = blockIdx.x;
  const bool hB = (bid >= NBLK8);
  const int blk = hB ? bid - NBLK8 : bid;
  const u16* f = hB ? inB : inA;
  const int* nbr = hB ? nbrB : nbrA;
  const u16* wf = hB ? wfB : wfA;
  float* st = hB ? stB : stA;

  constexpr bool FOLDED = (PHASE == 1);
  constexpr int KSTRIDE = FOLDED ? 5120 : 4096;

  // ---- stage weight fragments (frags 0-7 of each tap) into LDS -----------
#pragma unroll
  for (int j = 0; j < 9; ++j) {
    int idx = j * 512 + tid;        // uint4 index, 4608 = 9 taps x 512
    int tap = idx >> 9;
    int off = idx & 511;
    *(uint4*)(wlds + tap * 4096 + off * 8) =
        *(const uint4*)(wf + tap * KSTRIDE + off * 8);
  }
  __syncthreads();

  const int wv = tid >> 6;
  const int lane = tid & 63;
  const int lrow = lane & 31;
  const int lq = lane >> 5;
  const int base = blk * 256;
  const int gr = base + wv * 32 + lrow;

  int ids[9];
#pragma unroll
  for (int j = 0; j < 9; ++j) ids[j] = (gr < NVOX) ? nbr[gr * 9 + j] : NVOX;

  f32x16 acc0 = {0.f, 0.f, 0.f, 0.f, 0.f, 0.f, 0.f, 0.f,
                 0.f, 0.f, 0.f, 0.f, 0.f, 0.f, 0.f, 0.f};
  f32x16 acc1 = acc0;

#pragma unroll
  for (int k = 0; k < 9; ++k) {
    if (k != 4) {
      if (__ballot(ids[k] < NVOX) == 0ull) continue;
    }
    const int id = ids[k];
    const bool ok = id < NVOX;
    uint4 af[4];
    const u16* p = f + (size_t)id * 64 + lq * 8;
#pragma unroll
    for (int ksi = 0; ksi < 4; ++ksi) {
      uint4 v = make_uint4(0u, 0u, 0u, 0u);
      if (ok) v = *(const uint4*)(p + ksi * 16);
      af[ksi] = v;
    }
    const u16* wb = wlds + k * 4096;
#pragma unroll
    for (int ksi = 0; ksi < 4; ++ksi) {
      bf16x8 a = __builtin_bit_cast(bf16x8, af[ksi]);
      bf16x8 b0 = __builtin_bit_cast(bf16x8, *(const uint4*)(wb + (ksi * 2) * 512 + lane * 8));
      bf16x8 b1 = __builtin_bit_cast(bf16x8, *(const uint4*)(wb + (ksi * 2 + 1) * 512 + lane * 8));
      acc0 = __builtin_amdgcn_mfma_f32_32x32x16_bf16(a, b0, acc0, 0, 0, 0);
      acc1 = __builtin_amdgcn_mfma_f32_32x32x16_bf16(a, b1, acc1, 0, 0, 0);
    }
    if constexpr (FOLDED) {   // bias channel: A = 1[exists] at (lq=0, j=0); B from global
      uint4 a4 = make_uint4(0u, 0u, 0u, 0u);
      if (lq == 0 && ok) ((u16*)&a4)[0] = 0x3F80u;
      bf16x8 a = __builtin_bit_cast(bf16x8, a4);
      const u16* wg = wf + k * KSTRIDE;
      bf16x8 b0 = __builtin_bit_cast(bf16x8, *(const uint4*)(wg + 8 * 512 + lane * 8));
      bf16x8 b1 = __builtin_bit_cast(bf16x8, *(const uint4*)(wg + 9 * 512 + lane * 8));
      acc0 = __builtin_amdgcn_mfma_f32_32x32x16_bf16(a, b0, acc0, 0, 0, 0);
      acc1 = __builtin_amdgcn_mfma_f32_32x32x16_bf16(a, b1, acc1, 0, 0, 0);
    }
  }

  // ---- epilogue -----------------------------------------------------------
  // C/D (32x32): col = lane&31, row-in-wave = (reg&3) + 8*(reg>>2) + 4*(lane>>5)
  const int cc0 = lrow, cc1 = 32 + lrow;
  float s0 = 0.f, q0 = 0.f, s1 = 0.f, q1 = 0.f;
  float vout[2][16];
#pragma unroll
  for (int r = 0; r < 16; ++r) {
    float v = acc0[r]; v = v > 0.f ? v : 0.01f * v;
    s0 += v; q0 += v * v; vout[0][r] = v;
    float w = acc1[r]; w = w > 0.f ? w : 0.01f * w;
    s1 += w; q1 += w * w; vout[1][r] = w;
  }
  s0 += __shfl_xor(s0, 32); q0 += __shfl_xor(q0, 32);
  s1 += __shfl_xor(s1, 32); q1 += __shfl_xor(q1, 32);

  float* sredf = fbx;   // [8][128] alias, used before the bounce chunks
  if (lq == 0) {        // rows >= NVOX contribute exact 0
    sredf[wv * 128 + lrow] = s0;
    sredf[wv * 128 + 32 + lrow] = s1;
    sredf[wv * 128 + 64 + lrow] = q0;
    sredf[wv * 128 + 96 + lrow] = q1;
  }
  __syncthreads();
  if (tid < 128) {
    int which = tid >> 6, c = tid & 63;
    float v = 0.f;
#pragma unroll
    for (int w8 = 0; w8 < 8; ++w8) v += sredf[w8 * 128 + which * 64 + c];
    atomicAdd(&st[(bid & (NREP - 1)) * 128 + which * 64 + c], v);
  }
  __syncthreads();

  const bool f32out = (PHASE == 1) && !hB;
  float* yf = (float*)yA;
  u16* yb = (u16*)(hB ? yB : yA);
  u16* bbx = (u16*)fbx;   // u16 alias, stride 72
#pragma unroll
  for (int c = 0; c < 16; ++c) {        // chunk = 16 rows = half of wave c>>1
    if (wv == (c >> 1)) {
#pragma unroll
      for (int rr = 0; rr < 8; ++rr) {
        const int r = (c & 1) * 8 + rr;               // compile-time constant
        const int row16 = (r & 3) + 8 * ((r >> 2) & 1) + 4 * lq;
        if (f32out) {
          fbx[row16 * 68 + cc0] = vout[0][r];
          fbx[row16 * 68 + cc1] = vout[1][r];
        } else {
          bbx[row16 * 72 + cc0] = f2bf(vout[0][r]);
          bbx[row16 * 72 + cc1] = f2bf(vout[1][r]);
        }
      }
    }
    __syncthreads();
    const int row0 = base + c * 16;
    if (f32out) {
      if (tid < 256) {
        int rr = tid >> 4, cp = tid & 15, row = row0 + rr;
        if (row < NVOX)
          *(float4*)(yf + (size_t)row * 64 + cp * 4) = *(const float4*)(fbx + rr * 68 + cp * 4);
      }
    } else {
      if (tid < 128) {
        int rr = tid >> 3, cp = tid & 7, row = row0 + rr;
        if (row < NVOX)
          *(uint4*)(yb + (size_t)row * 64 + cp * 8) = *(const uint4*)(bbx + rr * 72 + cp * 8);
      }
    }
    __syncthreads();
  }
}

// ---- round-6 serial conv (fallback tiers) ---------------------------------
template <bool IN_F32, bool FOLDED, int MODE>
__global__ __launch_bounds__(256, 4)
void conv_k(const void* __restrict__ fv, const int* __restrict__ nbr,
            const u16* __restrict__ wf, void* yv, float* __restrict__ st,
            float* io, const float* __restrict__ affD,
            const float* __restrict__ affB) {
  __shared__ __align__(16) float fb[128 * 68];
  __shared__ float sred[4][128];

  const int tid = threadIdx.x;
  const int wv = tid >> 6;
  const int lane = tid & 63;
  const int lrow = lane & 31;
  const int lq = lane >> 5;
  const int base = blockIdx.x * TM;
  const int gr = base + wv * 32 + lrow;

  int ids[9];
#pragma unroll
  for (int j = 0; j < 9; ++j) ids[j] = (gr < NVOX) ? nbr[gr * 9 + j] : NVOX;

  f32x16 acc0 = {0.f, 0.f, 0.f, 0.f, 0.f, 0.f, 0.f, 0.f,
                 0.f, 0.f, 0.f, 0.f, 0.f, 0.f, 0.f, 0.f};
  f32x16 acc1 = acc0;
  constexpr int KSTRIDE = FOLDED ? 5120 : 4096;

#pragma unroll
  for (int k = 0; k < 9; ++k) {
    if (k != 4) {
      if (__ballot(ids[k] < NVOX) == 0ull) continue;
    }
    const int id = ids[k];
    const bool ok = id < NVOX;
    uint4 af[4];
    if constexpr (IN_F32) {
      const float* p = (const float*)fv + (size_t)id * 64 + lq * 8;
#pragma unroll
      for (int ksi = 0; ksi < 4; ++ksi) {
        uint4 v0 = make_uint4(0u, 0u, 0u, 0u), v1 = v0;
        if (ok) { v0 = *(const uint4*)(p + ksi * 16); v1 = *(const uint4*)(p + ksi * 16 + 4); }
        af[ksi] = cvt8(v0, v1);
      }
    } else {
      const u16* p = (const u16*)fv + (size_t)id * 64 + lq * 8;
#pragma unroll
      for (int ksi = 0; ksi < 4; ++ksi) {
        uint4 v = make_uint4(0u, 0u, 0u, 0u);
        if (ok) v = *(const uint4*)(p + ksi * 16);
        af[ksi] = v;
      }
    }
    const u16* wb = wf + k * KSTRIDE;
#pragma unroll
    for (int ksi = 0; ksi < 4; ++ksi) {
      bf16x8 a = __builtin_bit_cast(bf16x8, af[ksi]);
      bf16x8 b0 = __builtin_bit_cast(bf16x8, *(const uint4*)(wb + (ksi * 2) * 512 + lane * 8));
      bf16x8 b1 = __builtin_bit_cast(bf16x8, *(const uint4*)(wb + (ksi * 2 + 1) * 512 + lane * 8));
      acc0 = __builtin_amdgcn_mfma_f32_32x32x16_bf16(a, b0, acc0, 0, 0, 0);
      acc1 = __builtin_amdgcn_mfma_f32_32x32x16_bf16(a, b1, acc1, 0, 0, 0);
    }
    if constexpr (FOLDED) {
      uint4 a4 = make_uint4(0u, 0u, 0u, 0u);
      if (lq == 0 && ok) ((u16*)&a4)[0] = 0x3F80u;
      bf16x8 a = __builtin_bit_cast(bf16x8, a4);
      bf16x8 b0 = __builtin_bit_cast(bf16x8, *(const uint4*)(wb + 8 * 512 + lane * 8));
      bf16x8 b1 = __builtin_bit_cast(bf16x8, *(const uint4*)(wb + 9 * 512 + lane * 8));
      acc0 = __builtin_amdgcn_mfma_f32_32x32x16_bf16(a, b0, acc0, 0, 0, 0);
      acc1 = __builtin_amdgcn_mfma_f32_32x32x16_bf16(a, b1, acc1, 0, 0, 0);
    }
  }

  const int cc0 = lrow, cc1 = 32 + lrow;
  float aD0 = 0.f, aD1 = 0.f, hD0 = 0.f, hD1 = 0.f;
  if constexpr (MODE == 2) {
    aD0 = affD[cc0]; hD0 = affD[64 + cc0];
    aD1 = affD[cc1]; hD1 = affD[64 + cc1];
  }
  float s0 = 0.f, q0 = 0.f, s1 = 0.f, q1 = 0.f;
  float vout[2][16];
#pragma unroll
  for (int r = 0; r < 16; ++r) {
    float v = acc0[r]; v = v > 0.f ? v : 0.01f * v;
    s0 += v; q0 += v * v; vout[0][r] = v;
    float w = acc1[r]; w = w > 0.f ? w : 0.01f * w;
    s1 += w; q1 += w * w; vout[1][r] = w;
  }
  if constexpr (MODE != 2) {
    s0 += __shfl_xor(s0, 32); q0 += __shfl_xor(q0, 32);
    s1 += __shfl_xor(s1, 32); q1 += __shfl_xor(q1, 32);
    if (lq == 0) {
      sred[wv][lrow] = s0; sred[wv][32 + lrow] = s1;
      sred[wv][64 + lrow] = q0; sred[wv][96 + lrow] = q1;
    }
  }
  if constexpr (MODE == 0) {
    u16* bb = (u16*)fb;
#pragma unroll
    for (int r = 0; r < 16; ++r) {
      int rowD = 32 * wv + (r & 3) + 8 * (r >> 2) + 4 * lq;
      bb[rowD * 72 + cc0] = f2bf(vout[0][r]);
      bb[rowD * 72 + cc1] = f2bf(vout[1][r]);
    }
  } else if constexpr (MODE == 2 || MODE == 3) {
#pragma unroll
    for (int r = 0; r < 16; ++r) {
      int rowD = 32 * wv + (r & 3) + 8 * (r >> 2) + 4 * lq;
      float v0 = vout[0][r], v1 = vout[1][r];
      if constexpr (MODE == 2) { v0 = fmaf(v0, aD0, hD0); v1 = fmaf(v1, aD1, hD1); }
      fb[rowD * 68 + cc0] = v0;
      fb[rowD * 68 + cc1] = v1;
    }
  }
  __syncthreads();

  const int trow = tid >> 3, cp = tid & 7;
  if constexpr (MODE == 0) {
    u16* y = (u16*)yv;
    const u16* bb = (const u16*)fb;
#pragma unroll
    for (int it = 0; it < 4; ++it) {
      int r = it * 32 + trow, row = base + r;
      if (row < NVOX)
        *(uint4*)(y + (size_t)row * 64 + cp * 8) = *(const uint4*)(bb + r * 72 + cp * 8);
    }
  }
  if constexpr (MODE == 3) {
    float* y = (float*)yv;
#pragma unroll
    for (int it = 0; it < 4; ++it) {
      int r = it * 32 + trow, row = base + r;
      if (row < NVOX) {
        *(float4*)(y + (size_t)row * 64 + cp * 8) = *(const float4*)(fb + r * 68 + cp * 8);
        *(float4*)(y + (size_t)row * 64 + cp * 8 + 4) = *(const float4*)(fb + r * 68 + cp * 8 + 4);
      }
    }
  }
  if constexpr (MODE == 2) {
    float* y = (float*)yv;
#pragma unroll
    for (int it = 0; it < 4; ++it) {
      int r = it * 32 + trow, row = base + r;
      if (row < NVOX) {
        float t[8], p[8], o[8];
        *(float4*)&t[0] = *(const float4*)(fb + r * 68 + cp * 8);
        *(float4*)&t[4] = *(const float4*)(fb + r * 68 + cp * 8 + 4);
        *(float4*)&p[0] = *(const float4*)(io + (size_t)row * 64 + cp * 8);
        *(float4*)&p[4] = *(const float4*)(io + (size_t)row * 64 + cp * 8 + 4);
#pragma unroll
        for (int j = 0; j < 8; ++j) {
          int c = cp * 8 + j;
          o[j] = t[j] + fmaf(p[j], affB[c], affB[64 + c]);
        }
        *(float4*)(y + (size_t)row * 64 + cp * 8) = *(const float4*)&o[0];
        *(float4*)(y + (size_t)row * 64 + cp * 8 + 4) = *(const float4*)&o[4];
      }
    }
  }
  if constexpr (MODE != 2) {
    if (tid < 128) {
      int which = tid >> 6, c = tid & 63;
      float v = sred[0][which * 64 + c] + sred[1][which * 64 + c] +
                sred[2][which * 64 + c] + sred[3][which * 64 + c];
      atomicAdd(&st[(blockIdx.x & (NREP - 1)) * 128 + which * 64 + c], v);
    }
  }
}

// prep: feat fp32 -> bf16, raw weight fragments (w1, w2), zero stats + zero row
__global__ void prep_all(const float* __restrict__ feat, const float* __restrict__ w1,
                         const float* __restrict__ w2, u16* __restrict__ wf,
                         u16* __restrict__ F, float* __restrict__ st,
                         u16* __restrict__ zr, int cvt_blocks) {
  const int bid = blockIdx.x, tid = threadIdx.x;
  if (bid < cvt_blocks) {
    int i8 = (bid * 256 + tid) * 8;
    if (i8 < NVOX * 64) {
      uint4 a = *(const uint4*)(feat + i8);
      uint4 b = *(const uint4*)(feat + i8 + 4);
      *(uint4*)(F + i8) = cvt8(a, b);
    }
    return;
  }
  int rb = bid - cvt_blocks;
  if (rb < 288) {   // raw frags: [slot 0|1][k][ks*2+ct][lane][j]
    int e = rb * 256 + tid;
    int slot = e / 36864, r = e % 36864;
    int k = r >> 12, rr = r & 4095;
    int frag = rr >> 9, lane = (rr >> 3) & 63, j = rr & 7;
    int ks = frag >> 1, ct = frag & 1;
    int cin = ks * 16 + (lane >> 5) * 8 + j;
    int cout = ct * 32 + (lane & 31);
    const float* src = slot ? w2 : w1;
    wf[e] = f2bf(src[k * 4096 + cin * 64 + cout]);
    return;
  }
  for (int i = tid; i < 4 * STG; i += 256) st[i] = 0.f;
  if (tid < 32) ((u32*)zr)[tid] = 0u;   // shared 128 B zero row
}

__device__ __forceinline__ void bn_from_replicas(const float* stp, const float* g,
                                                 const float* b, int c,
                                                 float* sc, float* sh) {
  float s = 0.f, q = 0.f;
#pragma unroll
  for (int r = 0; r < NREP; ++r) {
    s += stp[r * 128 + c];
    q += stp[r * 128 + 64 + c];
  }
  const float invn = 1.0f / (float)NVOX;
  float mean = s * invn;
  float var = q * invn - mean * mean;
  float sca = g[c] * rsqrtf(var + 1e-5f);
  *sc = sca;
  *sh = b[c] - mean * sca;
}

// fold both BN stages into both second-conv weights (one dispatch, 360 blocks)
__global__ void wscale2(const float* __restrict__ wA, float* __restrict__ stpA,
                        const float* __restrict__ gA, const float* __restrict__ bA,
                        u16* __restrict__ dA,
                        const float* __restrict__ wB, float* __restrict__ stpB,
                        const float* __restrict__ gB, const float* __restrict__ bB,
                        u16* __restrict__ dB) {
  __shared__ float sc[64], sh[64];
  const int tid = threadIdx.x;
  const bool hB = (blockIdx.x >= 180);
  const float* wraw = hB ? wB : wA;
  float* stp = hB ? stpB : stpA;
  const float* g = hB ? gB : gA;
  const float* b = hB ? bB : bA;
  u16* dst = hB ? dB : dA;
  const int blk = hB ? blockIdx.x - 180 : blockIdx.x;
  if (tid < 64) {
    float a, h;
    bn_from_replicas(stp, g, b, tid, &a, &h);
    sc[tid] = a; sh[tid] = h;
    if (blk == 0) { stp[NREP * 128 + tid] = a; stp[NREP * 128 + 64 + tid] = h; }
  }
  __syncthreads();
  int e = blk * 256 + tid;   // [0, 46080)
  int k = e / 5120, r = e % 5120;
  int frag = r >> 9, lane = (r >> 3) & 63, j = r & 7;
  int ks = frag >> 1, ct = frag & 1;
  int cout = ct * 32 + (lane & 31);
  u16 val = 0;
  if (ks < 4) {
    int cin = ks * 16 + (lane >> 5) * 8 + j;
    val = f2bf(sc[cin] * wraw[k * 4096 + cin * 64 + cout]);
  } else if (((lane >> 5) == 0) && j == 0) {
    float acc = 0.f;
    for (int c = 0; c < 64; ++c) acc += sh[c] * wraw[k * 4096 + c * 64 + cout];
    val = f2bf(acc);
  }
  dst[e] = val;
}

// both output-BN affines in one tiny dispatch (fallback tiers)
__global__ void finalize2(float* __restrict__ stA, const float* __restrict__ gA,
                          const float* __restrict__ bA, float* __restrict__ stB,
                          const float* __restrict__ gB, const float* __restrict__ bB) {
  int t = threadIdx.x;
  float* stp = (t < 64) ? stA : stB;
  const float* g = (t < 64) ? gA : gB;
  const float* b = (t < 64) ? bA : bB;
  int c = t & 63;
  if (t < 128) {
    float a, h;
    bn_from_replicas(stp, g, b, c, &a, &h);
    stp[NREP * 128 + c] = a;
    stp[NREP * 128 + 64 + c] = h;
  }
}

// io (fp32, in place) = affB(io) + affD(y3 bf16)   (fallback tiers)
__global__ void final_add(const u16* __restrict__ y3, float* io,
                          const float* __restrict__ affB, const float* __restrict__ affD) {
  int i8 = (blockIdx.x * 256 + threadIdx.x) * 8;
  if (i8 < NVOX * 64) {
    float a[8];
    *(float4*)&a[0] = *(const float4*)(io + i8);
    *(float4*)&a[4] = *(const float4*)(io + i8 + 4);
    uint4 vd = *(const uint4*)(y3 + i8);
    const u16* pd = (const u16*)&vd;
    int cb = i8 & 63;
    float o[8];
#pragma unroll
    for (int j = 0; j < 8; ++j) {
      int c = cb + j;
      o[j] = fmaf(a[j], affB[c], affB[64 + c]) + fmaf(bf2f(pd[j]), affD[c], affD[64 + c]);
    }
    *(float4*)(io + i8) = *(const float4*)&o[0];
    *(float4*)(io + i8 + 4) = *(const float4*)&o[4];
  }
}

// fused tier: finalize2 + final_add merged (affines computed per-block in LDS)
__global__ void final_add2(const u16* __restrict__ y3, float* io,
                           float* __restrict__ stB, const float* __restrict__ gB,
                           const float* __restrict__ bB,
                           float* __restrict__ stD, const float* __restrict__ gD,
                           const float* __restrict__ bD) {
  __shared__ float aff[4][64];   // [B scale][B shift][D scale][D shift]
  const int t = threadIdx.x;
  if (t < 128) {
    float a, h;
    if (t < 64) { bn_from_replicas(stB, gB, bB, t, &a, &h); aff[0][t] = a; aff[1][t] = h; }
    else { int c = t - 64; bn_from_replicas(stD, gD, bD, c, &a, &h); aff[2][c] = a; aff[3][c] = h; }
  }
  __syncthreads();
  int i8 = (blockIdx.x * 256 + t) * 8;
  if (i8 < NVOX * 64) {
    float a[8];
    *(float4*)&a[0] = *(const float4*)(io + i8);
    *(float4*)&a[4] = *(const float4*)(io + i8 + 4);
    uint4 vd = *(const uint4*)(y3 + i8);
    const u16* pd = (const u16*)&vd;
    int cb = i8 & 63;
    float o[8];
#pragma unroll
    for (int j = 0; j < 8; ++j) {
      int c = cb + j;
      o[j] = fmaf(a[j], aff[0][c], aff[1][c]) + fmaf(bf2f(pd[j]), aff[2][c], aff[3][c]);
    }
    *(float4*)(io + i8) = *(const float4*)&o[0];
    *(float4*)(io + i8 + 4) = *(const float4*)&o[4];
  }
}

extern "C" void kernel_launch(void* const* d_in, const int* in_sizes, int n_in,
                              void* d_out, int out_size, void* d_ws, size_t ws_size,
                              hipStream_t stream) {
  const float* feat = (const float*)d_in[0];
  const float* w1 = (const float*)d_in[1];
  const float* w1_2 = (const float*)d_in[2];
  const float* w2 = (const float*)d_in[3];
  const float* w3 = (const float*)d_in[4];
  const float* g0 = (const float*)d_in[5];
  const float* b0 = (const float*)d_in[6];
  const float* g0_2 = (const float*)d_in[7];
  const float* b0_2 = (const float*)d_in[8];
  const float* g1 = (const float*)d_in[9];
  const float* b1 = (const float*)d_in[10];
  const float* g2 = (const float*)d_in[11];
  const float* b2 = (const float*)d_in[12];
  const int* nbr13 = (const int*)d_in[13];
  const int* nbr31 = (const int*)d_in[14];
  float* out = (float*)d_out;

  char* ws = (char*)d_ws;
  float* st = (float*)ws;                         // 4 stages x 4224 f = 67,584 B
  u16* wf = (u16*)(ws + 67584);                   // 331,776 B of fragments
  u16* s0 = wf;                                   // w1 raw      (36,864 u16)
  u16* s1 = wf + 36864;                           // w2 raw
  u16* s2 = wf + 73728;                           // w1_2 folded (46,080 u16)
  u16* s3 = wf + 119808;                          // w3 folded
  u16* zr = (u16*)(ws + 399360);                  // shared zero row, 128 B
  u16* F = (u16*)(ws + 399488);                   // feat bf16 (later Y3), 25.6 MB
  u16* A1 = F + (size_t)NVOX * 64;                // 25.6 MB
  u16* A2 = A1 + (size_t)NVOX * 64;               // 25.6 MB (fused plan only)
  const size_t base_sz = 399488;
  const size_t need_fused = base_sz + 3ull * NVOX * 64 * 2;
  const size_t need_serial = base_sz + 2ull * NVOX * 64 * 2;

  float* st0 = st, *st1 = st + STG, *st2 = st + 2 * STG, *st3 = st + 3 * STG;

  if (ws_size >= need_fused) {
    prep_all<<<6539, 256, 0, stream>>>(feat, w1, w2, wf, F, st, zr, 6250);
    // convA: conv1(F,nbr13,s0)->A1,st0  ||  conv2(F,nbr31,s1)->A2,st2
    conv_fused<0><<<2 * NBLK8, 512, 0, stream>>>(F, F, nbr13, nbr31, s0, s1, zr,
                                                 A1, A2, st0, st2);
    wscale2<<<360, 256, 0, stream>>>(w1_2, st0, g0, b0, s2, w3, st2, g1, b1, s3);
    // convB: conv1_2(A1,nbr31,s2)->out fp32,st1  ||  conv3(A2,nbr13,s3)->F bf16,st3
    conv_fused<1><<<2 * NBLK8, 512, 0, stream>>>(A1, A2, nbr31, nbr13, s2, s3, zr,
                                                 out, F, st1, st3);
    final_add2<<<6250, 256, 0, stream>>>(F, out, st1, g0_2, b0_2, st3, g2, b2);
  } else if (ws_size >= need_serial) {
    prep_all<<<6539, 256, 0, stream>>>(feat, w1, w2, wf, F, st, zr, 6250);
    conv_k<false, false, 0><<<NBLK, 256, 0, stream>>>(F, nbr13, s0, A1, st0, nullptr, nullptr, nullptr);
    wscale2<<<180, 256, 0, stream>>>(w1_2, st0, g0, b0, s2, w3, st2, g1, b1, s3);  // only half used
    conv_k<false, true, 3><<<NBLK, 256, 0, stream>>>(A1, nbr31, s2, out, st1, nullptr, nullptr, nullptr);
    conv_k<false, false, 0><<<NBLK, 256, 0, stream>>>(F, nbr31, s1, A1, st2, nullptr, nullptr, nullptr);
    wscale2<<<360, 256, 0, stream>>>(w1_2, st0, g0, b0, s2, w3, st2, g1, b1, s3);
    conv_k<false, true, 0><<<NBLK, 256, 0, stream>>>(A1, nbr13, s3, F, st3, nullptr, nullptr, nullptr);
    finalize2<<<1, 128, 0, stream>>>(st1, g0_2, b0_2, st3, g2, b2);
    final_add<<<6250, 256, 0, stream>>>(F, out, st1 + NREP * 128, st3 + NREP * 128);
  } else {
    // minimal-ws: recompute path (round-6 small)
    u16* Az = F;
    prep_all<<<289, 256, 0, stream>>>(feat, w1, w2, wf, nullptr, st, zr, 0);
    conv_k<true, false, 0><<<NBLK, 256, 0, stream>>>(feat, nbr13, s0, Az, st0, nullptr, nullptr, nullptr);
    wscale2<<<180, 256, 0, stream>>>(w1_2, st0, g0, b0, s2, w3, st2, g1, b1, s3);
    conv_k<false, true, 3><<<NBLK, 256, 0, stream>>>(Az, nbr31, s2, out, st1, nullptr, nullptr, nullptr);
    finalize2<<<1, 128, 0, stream>>>(st1, g0_2, b0_2, st3, g2, b2);
    conv_k<true, false, 0><<<NBLK, 256, 0, stream>>>(feat, nbr31, s1, Az, st2, nullptr, nullptr, nullptr);
    wscale2<<<360, 256, 0, stream>>>(w1_2, st0, g0, b0, s2, w3, st2, g1, b1, s3);
    conv_k<false, true, 1><<<NBLK, 256, 0, stream>>>(Az, nbr13, s3, nullptr, st3, nullptr, nullptr, nullptr);
    finalize2<<<1, 128, 0, stream>>>(st1, g0_2, b0_2, st3, g2, b2);
    conv_k<false, true, 2><<<NBLK, 256, 0, stream>>>(Az, nbr13, s3, out, nullptr, out,
                                                     st3 + NREP * 128, st1 + NREP * 128);
  }
}

// Round 6
// 258.093 us; speedup vs baseline: 2.6609x; 1.0682x over previous
//
#include <hip/hip_runtime.h>

#define NVOX 200000
#define TM 128
#define NBLK 1563   // ceil(200000/128)
#define NREP 32     // stats-accumulator replicas
#define STG 4224    // floats per stage: 32*128 replicas + 64 scale + 64 shift

typedef unsigned short u16;
typedef unsigned int u32;
typedef __bf16 bf16x8 __attribute__((ext_vector_type(8)));
typedef float f32x16 __attribute__((ext_vector_type(16)));

__device__ __forceinline__ float bf2f(u16 h) { return __uint_as_float(((u32)h) << 16); }
__device__ __forceinline__ u16 f2bf(float x) {
  u32 u = __float_as_uint(x);
  u32 r = u + 0x7fffu + ((u >> 16) & 1u);   // RNE
  return (u16)(r >> 16);
}
__device__ __forceinline__ uint4 cvt8(uint4 a, uint4 b) {
  const float* fa = (const float*)&a;
  const float* fb = (const float*)&b;
  uint4 r;
  u16* q = (u16*)&r;
#pragma unroll
  for (int j = 0; j < 4; ++j) { q[j] = f2bf(fa[j]); q[4 + j] = f2bf(fb[j]); }
  return r;
}

// ---------------------------------------------------------------------------
// Fused conv pair, round 12: round-0 body (best measured) with the occupancy
// bound raised.  __launch_bounds__(256,6) caps unified regs at 85 (k-loop
// peak ~72: 32 acc + 16 af + 9 ids + addressing) -> 6 blocks/CU = 24 waves/CU
// (was 4 blocks at min-bound 4, 40% occupancy).  Latency-stall theory: per
// wave-tap only ~36 instructions but ~9000 wave-cycles observed; gathers and
// weight loads miss L2 -> need TLP, which min-bound 4 was silently capping.
// PHASE 0 (convA): raw weights; both streams -> bf16 + stats.
// PHASE 1 (convB): folded weights (+bias K-step); stream A -> fp32 out + stats,
//                  stream B -> bf16 + stats.
// ---------------------------------------------------------------------------
template <int PHASE>
__global__ __launch_bounds__(256, 6)
void conv_fused(const u16* __restrict__ inA, const u16* __restrict__ inB,
                const int* __restrict__ nbrA, const int* __restrict__ nbrB,
                const u16* __restrict__ wfA, const u16* __restrict__ wfB,
                void* yA, void* yB, float* __restrict__ stA, float* __restrict__ stB) {
  __shared__ __align__(16) float fb4[64 * 68];   // 17,408 B (u16 alias [64][72])
  __shared__ float sred[4][128];

  const int tid = threadIdx.x;
  const int bid = blockIdx.x;
  const bool hB = (bid >= NBLK);
  const int blk = hB ? bid - NBLK : bid;
  const u16* f = hB ? inB : inA;
  const int* nbr = hB ? nbrB : nbrA;
  const u16* wf = hB ? wfB : wfA;
  float* st = hB ? stB : stA;

  const int wv = tid >> 6;
  const int lane = tid & 63;
  const int lrow = lane & 31;
  const int lq = lane >> 5;
  const int base = blk * TM;
  const int gr = base + wv * 32 + lrow;

  int ids[9];
#pragma unroll
  for (int j = 0; j < 9; ++j) ids[j] = (gr < NVOX) ? nbr[gr * 9 + j] : NVOX;

  f32x16 acc0 = {0.f, 0.f, 0.f, 0.f, 0.f, 0.f, 0.f, 0.f,
                 0.f, 0.f, 0.f, 0.f, 0.f, 0.f, 0.f, 0.f};
  f32x16 acc1 = acc0;
  constexpr bool FOLDED = (PHASE == 1);
  constexpr int KSTRIDE = FOLDED ? 5120 : 4096;

#pragma unroll
  for (int k = 0; k < 9; ++k) {
    if (k != 4) {
      if (__ballot(ids[k] < NVOX) == 0ull) continue;
    }
    const int id = ids[k];
    const bool ok = id < NVOX;
    uint4 af[4];
    const u16* p = f + (size_t)id * 64 + lq * 8;
#pragma unroll
    for (int ksi = 0; ksi < 4; ++ksi) {
      uint4 v = make_uint4(0u, 0u, 0u, 0u);
      if (ok) v = *(const uint4*)(p + ksi * 16);
      af[ksi] = v;
    }
    const u16* wb = wf + k * KSTRIDE;
#pragma unroll
    for (int ksi = 0; ksi < 4; ++ksi) {
      bf16x8 a = __builtin_bit_cast(bf16x8, af[ksi]);
      bf16x8 b0 = __builtin_bit_cast(bf16x8, *(const uint4*)(wb + (ksi * 2) * 512 + lane * 8));
      bf16x8 b1 = __builtin_bit_cast(bf16x8, *(const uint4*)(wb + (ksi * 2 + 1) * 512 + lane * 8));
      acc0 = __builtin_amdgcn_mfma_f32_32x32x16_bf16(a, b0, acc0, 0, 0, 0);
      acc1 = __builtin_amdgcn_mfma_f32_32x32x16_bf16(a, b1, acc1, 0, 0, 0);
    }
    if constexpr (FOLDED) {   // bias channel: A = 1[exists] at (lq=0, j=0)
      uint4 a4 = make_uint4(0u, 0u, 0u, 0u);
      if (lq == 0 && ok) ((u16*)&a4)[0] = 0x3F80u;
      bf16x8 a = __builtin_bit_cast(bf16x8, a4);
      bf16x8 b0 = __builtin_bit_cast(bf16x8, *(const uint4*)(wb + 8 * 512 + lane * 8));
      bf16x8 b1 = __builtin_bit_cast(bf16x8, *(const uint4*)(wb + 9 * 512 + lane * 8));
      acc0 = __builtin_amdgcn_mfma_f32_32x32x16_bf16(a, b0, acc0, 0, 0, 0);
      acc1 = __builtin_amdgcn_mfma_f32_32x32x16_bf16(a, b1, acc1, 0, 0, 0);
    }
  }

  // Epilogue. C/D (32x32): col = lane&31, row = (reg&3) + 8*(reg>>2) + 4*(lane>>5)
  const int cc0 = lrow, cc1 = 32 + lrow;
  float s0 = 0.f, q0 = 0.f, s1 = 0.f, q1 = 0.f;
  float vout[2][16];
#pragma unroll
  for (int r = 0; r < 16; ++r) {
    float v = acc0[r]; v = v > 0.f ? v : 0.01f * v;
    s0 += v; q0 += v * v; vout[0][r] = v;
    float w = acc1[r]; w = w > 0.f ? w : 0.01f * w;
    s1 += w; q1 += w * w; vout[1][r] = w;
  }
  s0 += __shfl_xor(s0, 32); q0 += __shfl_xor(q0, 32);
  s1 += __shfl_xor(s1, 32); q1 += __shfl_xor(q1, 32);
  if (lq == 0) {   // rows >= NVOX contribute exact 0
    sred[wv][lrow] = s0; sred[wv][32 + lrow] = s1;
    sred[wv][64 + lrow] = q0; sred[wv][96 + lrow] = q1;
  }

  const bool f32out = (PHASE == 1) && !hB;
  const int trow = tid >> 3, cp = tid & 7;
  u16* bb = (u16*)fb4;
#pragma unroll
  for (int h = 0; h < 2; ++h) {
    __syncthreads();
    if ((wv >> 1) == h) {
      const int lr = 32 * (wv & 1);
#pragma unroll
      for (int r = 0; r < 16; ++r) {
        int rowD = lr + (r & 3) + 8 * (r >> 2) + 4 * lq;
        if (f32out) {
          fb4[rowD * 68 + cc0] = vout[0][r];
          fb4[rowD * 68 + cc1] = vout[1][r];
        } else {
          bb[rowD * 72 + cc0] = f2bf(vout[0][r]);
          bb[rowD * 72 + cc1] = f2bf(vout[1][r]);
        }
      }
    }
    __syncthreads();
    if (f32out) {
      float* y = (float*)yA;
#pragma unroll
      for (int it = 0; it < 2; ++it) {
        int r = it * 32 + trow, row = base + 64 * h + r;
        if (row < NVOX) {
          *(float4*)(y + (size_t)row * 64 + cp * 8) = *(const float4*)(fb4 + r * 68 + cp * 8);
          *(float4*)(y + (size_t)row * 64 + cp * 8 + 4) = *(const float4*)(fb4 + r * 68 + cp * 8 + 4);
        }
      }
    } else {
      u16* y = (u16*)(hB ? yB : yA);
#pragma unroll
      for (int it = 0; it < 2; ++it) {
        int r = it * 32 + trow, row = base + 64 * h + r;
        if (row < NVOX)
          *(uint4*)(y + (size_t)row * 64 + cp * 8) = *(const uint4*)(bb + r * 72 + cp * 8);
      }
    }
  }
  if (tid < 128) {
    int which = tid >> 6, c = tid & 63;
    float v = sred[0][which * 64 + c] + sred[1][which * 64 + c] +
              sred[2][which * 64 + c] + sred[3][which * 64 + c];
    atomicAdd(&st[(bid & (NREP - 1)) * 128 + which * 64 + c], v);
  }
}

// ---- round-6 serial conv (fallback tiers) ---------------------------------
template <bool IN_F32, bool FOLDED, int MODE>
__global__ __launch_bounds__(256, 4)
void conv_k(const void* __restrict__ fv, const int* __restrict__ nbr,
            const u16* __restrict__ wf, void* yv, float* __restrict__ st,
            float* io, const float* __restrict__ affD,
            const float* __restrict__ affB) {
  __shared__ __align__(16) float fb[128 * 68];
  __shared__ float sred[4][128];

  const int tid = threadIdx.x;
  const int wv = tid >> 6;
  const int lane = tid & 63;
  const int lrow = lane & 31;
  const int lq = lane >> 5;
  const int base = blockIdx.x * TM;
  const int gr = base + wv * 32 + lrow;

  int ids[9];
#pragma unroll
  for (int j = 0; j < 9; ++j) ids[j] = (gr < NVOX) ? nbr[gr * 9 + j] : NVOX;

  f32x16 acc0 = {0.f, 0.f, 0.f, 0.f, 0.f, 0.f, 0.f, 0.f,
                 0.f, 0.f, 0.f, 0.f, 0.f, 0.f, 0.f, 0.f};
  f32x16 acc1 = acc0;
  constexpr int KSTRIDE = FOLDED ? 5120 : 4096;

#pragma unroll
  for (int k = 0; k < 9; ++k) {
    if (k != 4) {
      if (__ballot(ids[k] < NVOX) == 0ull) continue;
    }
    const int id = ids[k];
    const bool ok = id < NVOX;
    uint4 af[4];
    if constexpr (IN_F32) {
      const float* p = (const float*)fv + (size_t)id * 64 + lq * 8;
#pragma unroll
      for (int ksi = 0; ksi < 4; ++ksi) {
        uint4 v0 = make_uint4(0u, 0u, 0u, 0u), v1 = v0;
        if (ok) { v0 = *(const uint4*)(p + ksi * 16); v1 = *(const uint4*)(p + ksi * 16 + 4); }
        af[ksi] = cvt8(v0, v1);
      }
    } else {
      const u16* p = (const u16*)fv + (size_t)id * 64 + lq * 8;
#pragma unroll
      for (int ksi = 0; ksi < 4; ++ksi) {
        uint4 v = make_uint4(0u, 0u, 0u, 0u);
        if (ok) v = *(const uint4*)(p + ksi * 16);
        af[ksi] = v;
      }
    }
    const u16* wb = wf + k * KSTRIDE;
#pragma unroll
    for (int ksi = 0; ksi < 4; ++ksi) {
      bf16x8 a = __builtin_bit_cast(bf16x8, af[ksi]);
      bf16x8 b0 = __builtin_bit_cast(bf16x8, *(const uint4*)(wb + (ksi * 2) * 512 + lane * 8));
      bf16x8 b1 = __builtin_bit_cast(bf16x8, *(const uint4*)(wb + (ksi * 2 + 1) * 512 + lane * 8));
      acc0 = __builtin_amdgcn_mfma_f32_32x32x16_bf16(a, b0, acc0, 0, 0, 0);
      acc1 = __builtin_amdgcn_mfma_f32_32x32x16_bf16(a, b1, acc1, 0, 0, 0);
    }
    if constexpr (FOLDED) {
      uint4 a4 = make_uint4(0u, 0u, 0u, 0u);
      if (lq == 0 && ok) ((u16*)&a4)[0] = 0x3F80u;
      bf16x8 a = __builtin_bit_cast(bf16x8, a4);
      bf16x8 b0 = __builtin_bit_cast(bf16x8, *(const uint4*)(wb + 8 * 512 + lane * 8));
      bf16x8 b1 = __builtin_bit_cast(bf16x8, *(const uint4*)(wb + 9 * 512 + lane * 8));
      acc0 = __builtin_amdgcn_mfma_f32_32x32x16_bf16(a, b0, acc0, 0, 0, 0);
      acc1 = __builtin_amdgcn_mfma_f32_32x32x16_bf16(a, b1, acc1, 0, 0, 0);
    }
  }

  const int cc0 = lrow, cc1 = 32 + lrow;
  float aD0 = 0.f, aD1 = 0.f, hD0 = 0.f, hD1 = 0.f;
  if constexpr (MODE == 2) {
    aD0 = affD[cc0]; hD0 = affD[64 + cc0];
    aD1 = affD[cc1]; hD1 = affD[64 + cc1];
  }
  float s0 = 0.f, q0 = 0.f, s1 = 0.f, q1 = 0.f;
  float vout[2][16];
#pragma unroll
  for (int r = 0; r < 16; ++r) {
    float v = acc0[r]; v = v > 0.f ? v : 0.01f * v;
    s0 += v; q0 += v * v; vout[0][r] = v;
    float w = acc1[r]; w = w > 0.f ? w : 0.01f * w;
    s1 += w; q1 += w * w; vout[1][r] = w;
  }
  if constexpr (MODE != 2) {
    s0 += __shfl_xor(s0, 32); q0 += __shfl_xor(q0, 32);
    s1 += __shfl_xor(s1, 32); q1 += __shfl_xor(q1, 32);
    if (lq == 0) {
      sred[wv][lrow] = s0; sred[wv][32 + lrow] = s1;
      sred[wv][64 + lrow] = q0; sred[wv][96 + lrow] = q1;
    }
  }
  if constexpr (MODE == 0) {
    u16* bb = (u16*)fb;
#pragma unroll
    for (int r = 0; r < 16; ++r) {
      int rowD = 32 * wv + (r & 3) + 8 * (r >> 2) + 4 * lq;
      bb[rowD * 72 + cc0] = f2bf(vout[0][r]);
      bb[rowD * 72 + cc1] = f2bf(vout[1][r]);
    }
  } else if constexpr (MODE == 2 || MODE == 3) {
#pragma unroll
    for (int r = 0; r < 16; ++r) {
      int rowD = 32 * wv + (r & 3) + 8 * (r >> 2) + 4 * lq;
      float v0 = vout[0][r], v1 = vout[1][r];
      if constexpr (MODE == 2) { v0 = fmaf(v0, aD0, hD0); v1 = fmaf(v1, aD1, hD1); }
      fb[rowD * 68 + cc0] = v0;
      fb[rowD * 68 + cc1] = v1;
    }
  }
  __syncthreads();

  const int trow = tid >> 3, cp = tid & 7;
  if constexpr (MODE == 0) {
    u16* y = (u16*)yv;
    const u16* bb = (const u16*)fb;
#pragma unroll
    for (int it = 0; it < 4; ++it) {
      int r = it * 32 + trow, row = base + r;
      if (row < NVOX)
        *(uint4*)(y + (size_t)row * 64 + cp * 8) = *(const uint4*)(bb + r * 72 + cp * 8);
    }
  }
  if constexpr (MODE == 3) {
    float* y = (float*)yv;
#pragma unroll
    for (int it = 0; it < 4; ++it) {
      int r = it * 32 + trow, row = base + r;
      if (row < NVOX) {
        *(float4*)(y + (size_t)row * 64 + cp * 8) = *(const float4*)(fb + r * 68 + cp * 8);
        *(float4*)(y + (size_t)row * 64 + cp * 8 + 4) = *(const float4*)(fb + r * 68 + cp * 8 + 4);
      }
    }
  }
  if constexpr (MODE == 2) {
    float* y = (float*)yv;
#pragma unroll
    for (int it = 0; it < 4; ++it) {
      int r = it * 32 + trow, row = base + r;
      if (row < NVOX) {
        float t[8], p[8], o[8];
        *(float4*)&t[0] = *(const float4*)(fb + r * 68 + cp * 8);
        *(float4*)&t[4] = *(const float4*)(fb + r * 68 + cp * 8 + 4);
        *(float4*)&p[0] = *(const float4*)(io + (size_t)row * 64 + cp * 8);
        *(float4*)&p[4] = *(const float4*)(io + (size_t)row * 64 + cp * 8 + 4);
#pragma unroll
        for (int j = 0; j < 8; ++j) {
          int c = cp * 8 + j;
          o[j] = t[j] + fmaf(p[j], affB[c], affB[64 + c]);
        }
        *(float4*)(y + (size_t)row * 64 + cp * 8) = *(const float4*)&o[0];
        *(float4*)(y + (size_t)row * 64 + cp * 8 + 4) = *(const float4*)&o[4];
      }
    }
  }
  if constexpr (MODE != 2) {
    if (tid < 128) {
      int which = tid >> 6, c = tid & 63;
      float v = sred[0][which * 64 + c] + sred[1][which * 64 + c] +
                sred[2][which * 64 + c] + sred[3][which * 64 + c];
      atomicAdd(&st[(blockIdx.x & (NREP - 1)) * 128 + which * 64 + c], v);
    }
  }
}

// prep: feat fp32 -> bf16, raw weight fragments (w1, w2), zero stats + zero row
__global__ void prep_all(const float* __restrict__ feat, const float* __restrict__ w1,
                         const float* __restrict__ w2, u16* __restrict__ wf,
                         u16* __restrict__ F, float* __restrict__ st,
                         u16* __restrict__ zr, int cvt_blocks) {
  const int bid = blockIdx.x, tid = threadIdx.x;
  if (bid < cvt_blocks) {
    int i8 = (bid * 256 + tid) * 8;
    if (i8 < NVOX * 64) {
      uint4 a = *(const uint4*)(feat + i8);
      uint4 b = *(const uint4*)(feat + i8 + 4);
      *(uint4*)(F + i8) = cvt8(a, b);
    }
    return;
  }
  int rb = bid - cvt_blocks;
  if (rb < 288) {   // raw frags: [slot 0|1][k][ks*2+ct][lane][j]
    int e = rb * 256 + tid;
    int slot = e / 36864, r = e % 36864;
    int k = r >> 12, rr = r & 4095;
    int frag = rr >> 9, lane = (rr >> 3) & 63, j = rr & 7;
    int ks = frag >> 1, ct = frag & 1;
    int cin = ks * 16 + (lane >> 5) * 8 + j;
    int cout = ct * 32 + (lane & 31);
    const float* src = slot ? w2 : w1;
    wf[e] = f2bf(src[k * 4096 + cin * 64 + cout]);
    return;
  }
  for (int i = tid; i < 4 * STG; i += 256) st[i] = 0.f;
  if (tid < 32) ((u32*)zr)[tid] = 0u;   // shared 128 B zero row
}

__device__ __forceinline__ void bn_from_replicas(const float* stp, const float* g,
                                                 const float* b, int c,
                                                 float* sc, float* sh) {
  float s = 0.f, q = 0.f;
#pragma unroll
  for (int r = 0; r < NREP; ++r) {
    s += stp[r * 128 + c];
    q += stp[r * 128 + 64 + c];
  }
  const float invn = 1.0f / (float)NVOX;
  float mean = s * invn;
  float var = q * invn - mean * mean;
  float sca = g[c] * rsqrtf(var + 1e-5f);
  *sc = sca;
  *sh = b[c] - mean * sca;
}

// fold both BN stages into both second-conv weights (one dispatch, 360 blocks)
__global__ void wscale2(const float* __restrict__ wA, float* __restrict__ stpA,
                        const float* __restrict__ gA, const float* __restrict__ bA,
                        u16* __restrict__ dA,
                        const float* __restrict__ wB, float* __restrict__ stpB,
                        const float* __restrict__ gB, const float* __restrict__ bB,
                        u16* __restrict__ dB) {
  __shared__ float sc[64], sh[64];
  const int tid = threadIdx.x;
  const bool hB = (blockIdx.x >= 180);
  const float* wraw = hB ? wB : wA;
  float* stp = hB ? stpB : stpA;
  const float* g = hB ? gB : gA;
  const float* b = hB ? bB : bA;
  u16* dst = hB ? dB : dA;
  const int blk = hB ? blockIdx.x - 180 : blockIdx.x;
  if (tid < 64) {
    float a, h;
    bn_from_replicas(stp, g, b, tid, &a, &h);
    sc[tid] = a; sh[tid] = h;
    if (blk == 0) { stp[NREP * 128 + tid] = a; stp[NREP * 128 + 64 + tid] = h; }
  }
  __syncthreads();
  int e = blk * 256 + tid;   // [0, 46080)
  int k = e / 5120, r = e % 5120;
  int frag = r >> 9, lane = (r >> 3) & 63, j = r & 7;
  int ks = frag >> 1, ct = frag & 1;
  int cout = ct * 32 + (lane & 31);
  u16 val = 0;
  if (ks < 4) {
    int cin = ks * 16 + (lane >> 5) * 8 + j;
    val = f2bf(sc[cin] * wraw[k * 4096 + cin * 64 + cout]);
  } else if (((lane >> 5) == 0) && j == 0) {
    float acc = 0.f;
    for (int c = 0; c < 64; ++c) acc += sh[c] * wraw[k * 4096 + c * 64 + cout];
    val = f2bf(acc);
  }
  dst[e] = val;
}

// both output-BN affines in one tiny dispatch (fallback tiers)
__global__ void finalize2(float* __restrict__ stA, const float* __restrict__ gA,
                          const float* __restrict__ bA, float* __restrict__ stB,
                          const float* __restrict__ gB, const float* __restrict__ bB) {
  int t = threadIdx.x;
  float* stp = (t < 64) ? stA : stB;
  const float* g = (t < 64) ? gA : gB;
  const float* b = (t < 64) ? bA : bB;
  int c = t & 63;
  if (t < 128) {
    float a, h;
    bn_from_replicas(stp, g, b, c, &a, &h);
    stp[NREP * 128 + c] = a;
    stp[NREP * 128 + 64 + c] = h;
  }
}

// io (fp32, in place) = affB(io) + affD(y3 bf16)   (fallback tiers)
__global__ void final_add(const u16* __restrict__ y3, float* io,
                          const float* __restrict__ affB, const float* __restrict__ affD) {
  int i8 = (blockIdx.x * 256 + threadIdx.x) * 8;
  if (i8 < NVOX * 64) {
    float a[8];
    *(float4*)&a[0] = *(const float4*)(io + i8);
    *(float4*)&a[4] = *(const float4*)(io + i8 + 4);
    uint4 vd = *(const uint4*)(y3 + i8);
    const u16* pd = (const u16*)&vd;
    int cb = i8 & 63;
    float o[8];
#pragma unroll
    for (int j = 0; j < 8; ++j) {
      int c = cb + j;
      o[j] = fmaf(a[j], affB[c], affB[64 + c]) + fmaf(bf2f(pd[j]), affD[c], affD[64 + c]);
    }
    *(float4*)(io + i8) = *(const float4*)&o[0];
    *(float4*)(io + i8 + 4) = *(const float4*)&o[4];
  }
}

// fused tier: finalize2 + final_add merged (affines computed per-block in LDS)
__global__ void final_add2(const u16* __restrict__ y3, float* io,
                           float* __restrict__ stB, const float* __restrict__ gB,
                           const float* __restrict__ bB,
                           float* __restrict__ stD, const float* __restrict__ gD,
                           const float* __restrict__ bD) {
  __shared__ float aff[4][64];   // [B scale][B shift][D scale][D shift]
  const int t = threadIdx.x;
  if (t < 128) {
    float a, h;
    if (t < 64) { bn_from_replicas(stB, gB, bB, t, &a, &h); aff[0][t] = a; aff[1][t] = h; }
    else { int c = t - 64; bn_from_replicas(stD, gD, bD, c, &a, &h); aff[2][c] = a; aff[3][c] = h; }
  }
  __syncthreads();
  int i8 = (blockIdx.x * 256 + t) * 8;
  if (i8 < NVOX * 64) {
    float a[8];
    *(float4*)&a[0] = *(const float4*)(io + i8);
    *(float4*)&a[4] = *(const float4*)(io + i8 + 4);
    uint4 vd = *(const uint4*)(y3 + i8);
    const u16* pd = (const u16*)&vd;
    int cb = i8 & 63;
    float o[8];
#pragma unroll
    for (int j = 0; j < 8; ++j) {
      int c = cb + j;
      o[j] = fmaf(a[j], aff[0][c], aff[1][c]) + fmaf(bf2f(pd[j]), aff[2][c], aff[3][c]);
    }
    *(float4*)(io + i8) = *(const float4*)&o[0];
    *(float4*)(io + i8 + 4) = *(const float4*)&o[4];
  }
}

extern "C" void kernel_launch(void* const* d_in, const int* in_sizes, int n_in,
                              void* d_out, int out_size, void* d_ws, size_t ws_size,
                              hipStream_t stream) {
  const float* feat = (const float*)d_in[0];
  const float* w1 = (const float*)d_in[1];
  const float* w1_2 = (const float*)d_in[2];
  const float* w2 = (const float*)d_in[3];
  const float* w3 = (const float*)d_in[4];
  const float* g0 = (const float*)d_in[5];
  const float* b0 = (const float*)d_in[6];
  const float* g0_2 = (const float*)d_in[7];
  const float* b0_2 = (const float*)d_in[8];
  const float* g1 = (const float*)d_in[9];
  const float* b1 = (const float*)d_in[10];
  const float* g2 = (const float*)d_in[11];
  const float* b2 = (const float*)d_in[12];
  const int* nbr13 = (const int*)d_in[13];
  const int* nbr31 = (const int*)d_in[14];
  float* out = (float*)d_out;

  char* ws = (char*)d_ws;
  float* st = (float*)ws;                         // 4 stages x 4224 f = 67,584 B
  u16* wf = (u16*)(ws + 67584);                   // 331,776 B of fragments
  u16* s0 = wf;                                   // w1 raw      (36,864 u16)
  u16* s1 = wf + 36864;                           // w2 raw
  u16* s2 = wf + 73728;                           // w1_2 folded (46,080 u16)
  u16* s3 = wf + 119808;                          // w3 folded
  u16* zr = (u16*)(ws + 399360);                  // shared zero row, 128 B (unused by fused tier)
  u16* F = (u16*)(ws + 399488);                   // feat bf16 (later Y3), 25.6 MB
  u16* A1 = F + (size_t)NVOX * 64;                // 25.6 MB
  u16* A2 = A1 + (size_t)NVOX * 64;               // 25.6 MB (fused plan only)
  const size_t base_sz = 399488;
  const size_t need_fused = base_sz + 3ull * NVOX * 64 * 2;
  const size_t need_serial = base_sz + 2ull * NVOX * 64 * 2;

  float* st0 = st, *st1 = st + STG, *st2 = st + 2 * STG, *st3 = st + 3 * STG;

  if (ws_size >= need_fused) {
    prep_all<<<6539, 256, 0, stream>>>(feat, w1, w2, wf, F, st, zr, 6250);
    // convA: conv1(F,nbr13,s0)->A1,st0  ||  conv2(F,nbr31,s1)->A2,st2
    conv_fused<0><<<2 * NBLK, 256, 0, stream>>>(F, F, nbr13, nbr31, s0, s1,
                                                A1, A2, st0, st2);
    wscale2<<<360, 256, 0, stream>>>(w1_2, st0, g0, b0, s2, w3, st2, g1, b1, s3);
    // convB: conv1_2(A1,nbr31,s2)->out fp32,st1  ||  conv3(A2,nbr13,s3)->F bf16,st3
    conv_fused<1><<<2 * NBLK, 256, 0, stream>>>(A1, A2, nbr31, nbr13, s2, s3,
                                                out, F, st1, st3);
    final_add2<<<6250, 256, 0, stream>>>(F, out, st1, g0_2, b0_2, st3, g2, b2);
  } else if (ws_size >= need_serial) {
    prep_all<<<6539, 256, 0, stream>>>(feat, w1, w2, wf, F, st, zr, 6250);
    conv_k<false, false, 0><<<NBLK, 256, 0, stream>>>(F, nbr13, s0, A1, st0, nullptr, nullptr, nullptr);
    wscale2<<<180, 256, 0, stream>>>(w1_2, st0, g0, b0, s2, w3, st2, g1, b1, s3);  // only half used
    conv_k<false, true, 3><<<NBLK, 256, 0, stream>>>(A1, nbr31, s2, out, st1, nullptr, nullptr, nullptr);
    conv_k<false, false, 0><<<NBLK, 256, 0, stream>>>(F, nbr31, s1, A1, st2, nullptr, nullptr, nullptr);
    wscale2<<<360, 256, 0, stream>>>(w1_2, st0, g0, b0, s2, w3, st2, g1, b1, s3);
    conv_k<false, true, 0><<<NBLK, 256, 0, stream>>>(A1, nbr13, s3, F, st3, nullptr, nullptr, nullptr);
    finalize2<<<1, 128, 0, stream>>>(st1, g0_2, b0_2, st3, g2, b2);
    final_add<<<6250, 256, 0, stream>>>(F, out, st1 + NREP * 128, st3 + NREP * 128);
  } else {
    // minimal-ws: recompute path (round-6 small)
    u16* Az = F;
    prep_all<<<289, 256, 0, stream>>>(feat, w1, w2, wf, nullptr, st, zr, 0);
    conv_k<true, false, 0><<<NBLK, 256, 0, stream>>>(feat, nbr13, s0, Az, st0, nullptr, nullptr, nullptr);
    wscale2<<<180, 256, 0, stream>>>(w1_2, st0, g0, b0, s2, w3, st2, g1, b1, s3);
    conv_k<false, true, 3><<<NBLK, 256, 0, stream>>>(Az, nbr31, s2, out, st1, nullptr, nullptr, nullptr);
    finalize2<<<1, 128, 0, stream>>>(st1, g0_2, b0_2, st3, g2, b2);
    conv_k<true, false, 0><<<NBLK, 256, 0, stream>>>(feat, nbr31, s1, Az, st2, nullptr, nullptr, nullptr);
    wscale2<<<360, 256, 0, stream>>>(w1_2, st0, g0, b0, s2, w3, st2, g1, b1, s3);
    conv_k<false, true, 1><<<NBLK, 256, 0, stream>>>(Az, nbr13, s3, nullptr, st3, nullptr, nullptr, nullptr);
    finalize2<<<1, 128, 0, stream>>>(st1, g0_2, b0_2, st3, g2, b2);
    conv_k<false, true, 2><<<NBLK, 256, 0, stream>>>(Az, nbr13, s3, out, nullptr, out,
                                                     st3 + NREP * 128, st1 + NREP * 128);
  }
}